// Round 1
// 243.676 us; speedup vs baseline: 1.0347x; 1.0347x over previous
//
#include <hip/hip_runtime.h>
#include <hip/hip_bf16.h>

// MultiHeadAttention S=1024 B=4 D=1024 H=16 DH=64
// [0] prep: Wq/Wk/Wv/Wo f32 -> bf16 B^T[n][k]  (z=0..3)
//          query/key/value f32 -> bf16 row-major (z=4..15)
//          qA -> ws attn_out region (dead until attn); kA,vA -> d_out scratch.
// [1] qkv_gemm: pure-m97 128x128 GEMM, BOTH operands via global_load_lds.
//     Grid (row fastest) pins same-A-strip blocks to one XCD (r5: FETCH 200->49MB).
// [2] attn: flash-style, dbuf LDS, mask via accumulator-init bias.
//     R1: XCD-pinning swizzle (all 8 q-tiles of a (b,h) on one XCD -> K/V L2-resident),
//         sBias LDS table -> uniform-mask bit-select at acc init, s_setprio around MFMA.
// [3] out_gemm.
// ws (bf16 elems): q @0, k @NE, v @2NE, attn_out/qA @3NE, WT(4x1M) @4NE (40MB)

typedef __attribute__((ext_vector_type(8))) short short8;
typedef __attribute__((ext_vector_type(4))) short short4_;
typedef __attribute__((ext_vector_type(4))) float f32x4;
typedef __attribute__((ext_vector_type(16))) float f32x16;
typedef __attribute__((ext_vector_type(8))) __bf16 bf16x8;
typedef __attribute__((ext_vector_type(4))) __bf16 bf16x4;

union B8 {
    short8 s;
    bf16x8 b;
    unsigned short u[8];
};
union B4 {
    short4_ s;
    bf16x4 b;
    unsigned short u[4];
    int i[2];
};

#if __has_builtin(__builtin_amdgcn_exp2f)
#define EXP2(x) __builtin_amdgcn_exp2f(x)
#else
#define EXP2(x) exp2f(x)
#endif
#if __has_builtin(__builtin_amdgcn_rcpf)
#define RCP(x) __builtin_amdgcn_rcpf(x)
#else
#define RCP(x) (1.0f / (x))
#endif

static __device__ __forceinline__ unsigned short f2bf_rne(float f) {
    union { float f; unsigned u; } v; v.f = f;
    unsigned r = v.u + 0x7FFFu + ((v.u >> 16) & 1u);
    return (unsigned short)(r >> 16);
}

static __device__ __forceinline__ void async_lds16(const void* g, const void* l) {
    __builtin_amdgcn_global_load_lds(
        (const __attribute__((address_space(1))) unsigned int*)(unsigned long long)g,
        (__attribute__((address_space(3))) unsigned int*)(unsigned int)(unsigned long long)l,
        16, 0, 0);
}

// ---------------------------------------------------------------------------
// Prep: z<4 weight transpose+convert; z>=4 activation f32->bf16 convert.
// ---------------------------------------------------------------------------
__global__ __launch_bounds__(256) void prep(
    const float* __restrict__ Wq, const float* __restrict__ Wk,
    const float* __restrict__ Wv, const float* __restrict__ Wo,
    const float* __restrict__ query, const float* __restrict__ key,
    const float* __restrict__ value,
    unsigned short* __restrict__ WT,
    unsigned short* __restrict__ qA, unsigned short* __restrict__ kA,
    unsigned short* __restrict__ vA) {
    const int t = threadIdx.x;
    const int z = blockIdx.z;

    if (z >= 4) {
        // activation convert: 12 slices x 1M elems; 256 blocks x 4096 elems.
        const int zz = z - 4;
        const int tensor = zz >> 2;
        const int part = zz & 3;
        const float* src = (tensor == 0) ? query : (tensor == 1) ? key : value;
        unsigned short* dst = (tensor == 0) ? qA : (tensor == 1) ? kA : vA;
        const int blk = blockIdx.y * 16 + blockIdx.x;
        const size_t base = (size_t)part * 1048576 + (size_t)blk * 4096 + t * 16;
        B8 w0, w1;
#pragma unroll
        for (int i = 0; i < 2; ++i) {
            f32x4 a = *(const f32x4*)(src + base + i * 8);
            f32x4 b = *(const f32x4*)(src + base + i * 8 + 4);
#pragma unroll
            for (int j = 0; j < 4; ++j) {
                (i ? w1 : w0).u[j] = f2bf_rne(a[j]);
                (i ? w1 : w0).u[4 + j] = f2bf_rne(b[j]);
            }
        }
        *(short8*)(dst + base) = w0.s;
        *(short8*)(dst + base + 8) = w1.s;
        return;
    }

    __shared__ float sT[64][65];
    const int dtile = blockIdx.x;
    const int sub = blockIdx.y;
    const float* src;
    int spitch;
    unsigned short* dst;
    if (z < 3) {
        const float* W = (z == 0) ? Wq : (z == 1) ? Wk : Wv;
        src = W + (size_t)sub * 65536 + (size_t)dtile * 64 * 64;
        spitch = 64;
        dst = WT + (size_t)z * 1048576 + (size_t)(sub * 64) * 1024 + dtile * 64;
    } else {
        src = Wo + (size_t)dtile * 64 * 1024 + sub * 64;
        spitch = 1024;
        dst = WT + (size_t)3 * 1048576 + (size_t)(sub * 64) * 1024 + dtile * 64;
    }

    const int r = t >> 2;
    const int cseg = (t & 3) * 16;
#pragma unroll
    for (int i = 0; i < 4; ++i) {
        f32x4 v = *(const f32x4*)(src + (size_t)r * spitch + cseg + i * 4);
#pragma unroll
        for (int j = 0; j < 4; ++j) sT[r][cseg + i * 4 + j] = v[j];
    }
    __syncthreads();
    B8 w0, w1;
#pragma unroll
    for (int i = 0; i < 8; ++i) {
        w0.u[i] = f2bf_rne(sT[cseg + i][r]);
        w1.u[i] = f2bf_rne(sT[cseg + 8 + i][r]);
    }
    *(short8*)(dst + (size_t)r * 1024 + cseg) = w0.s;
    *(short8*)(dst + (size_t)r * 1024 + cseg + 8) = w1.s;
}

// ---------------------------------------------------------------------------
// 128x128-tile GEMM (BK=64), both operands bf16 via global_load_lds (m97 shape).
// blockIdx.x = row-tile (fastest -> XCD pinning), blockIdx.y = col-tile.
// ---------------------------------------------------------------------------
template <bool OUT_F32>
__device__ __forceinline__ void gemm128(const unsigned short* __restrict__ A,
                                        const unsigned short* __restrict__ Bt,
                                        const float* __restrict__ bias,
                                        void* __restrict__ Cv, float oscale) {
    __shared__ unsigned short sA[128 * 64];
    __shared__ unsigned short sB[128 * 64];
    const int t = threadIdx.x;
    const int w = t >> 6;
    const int lane = t & 63;
    const int quad = lane >> 4;
    const int l15 = lane & 15;
    const int wr = w >> 1;
    const int wc = w & 1;
    const int row0 = blockIdx.x * 128;
    const int col0 = blockIdx.y * 128;
    const int lrow8 = lane >> 3;
    const int lseg = lane & 7;

    f32x4 acc[4][4] = {};

    for (int k0 = 0; k0 < 1024; k0 += 64) {
#pragma unroll
        for (int i = 0; i < 4; ++i) {
            const int rr = w * 32 + i * 8;
            async_lds16(A + (size_t)(row0 + rr + lrow8) * 1024 + k0 + lseg * 8,
                        &sA[rr * 64]);
            async_lds16(Bt + (size_t)(col0 + rr + lrow8) * 1024 + k0 + lseg * 8,
                        &sB[rr * 64]);
        }
        __syncthreads();
#pragma unroll
        for (int kf = 0; kf < 2; ++kf) {
            B8 af[4], bf[4];
#pragma unroll
            for (int i = 0; i < 4; ++i)
                af[i].s = *(const short8*)&sA[(wr * 64 + i * 16 + l15) * 64 + kf * 32 + quad * 8];
#pragma unroll
            for (int j = 0; j < 4; ++j)
                bf[j].s = *(const short8*)&sB[(wc * 64 + j * 16 + l15) * 64 + kf * 32 + quad * 8];
#pragma unroll
            for (int i = 0; i < 4; ++i)
#pragma unroll
                for (int j = 0; j < 4; ++j)
                    acc[i][j] = __builtin_amdgcn_mfma_f32_16x16x32_bf16(af[i].b, bf[j].b,
                                                                        acc[i][j], 0, 0, 0);
        }
        __syncthreads();
    }
#pragma unroll
    for (int j = 0; j < 4; ++j) {
        const int col = col0 + wc * 64 + j * 16 + l15;
        const float bb = bias[col];
#pragma unroll
        for (int i = 0; i < 4; ++i) {
#pragma unroll
            for (int r = 0; r < 4; ++r) {
                const int row = row0 + wr * 64 + i * 16 + quad * 4 + r;
                const size_t idx = (size_t)row * 1024 + col;
                const float val = (acc[i][j][r] + bb) * oscale;
                if constexpr (OUT_F32)
                    ((float*)Cv)[idx] = val;
                else
                    ((unsigned short*)Cv)[idx] = f2bf_rne(val);
            }
        }
    }
}

#define SCALE_L2E 0.18033688011112042f  // (1/8) * log2(e)

__global__ __launch_bounds__(256) void qkv_gemm(
    const unsigned short* __restrict__ qA, const unsigned short* __restrict__ kA,
    const unsigned short* __restrict__ vA,
    const unsigned short* __restrict__ WT,
    const float* __restrict__ bq, const float* __restrict__ bk, const float* __restrict__ bv,
    unsigned short* q_o, unsigned short* k_o, unsigned short* v_o) {
    const int p = blockIdx.z;
    const unsigned short* A = (p == 0) ? qA : (p == 1) ? kA : vA;
    const unsigned short* Bt = WT + (size_t)p * 1048576;
    const float* bias = (p == 0) ? bq : (p == 1) ? bk : bv;
    unsigned short* C = (p == 0) ? q_o : (p == 1) ? k_o : v_o;
    const float osc = (p == 0) ? SCALE_L2E : 1.0f;  // pre-scale q for attn exp2
    gemm128<false>(A, Bt, bias, C, osc);
}

__global__ __launch_bounds__(256) void out_gemm(const unsigned short* __restrict__ A,
                                                const unsigned short* __restrict__ WT,
                                                const float* __restrict__ bo,
                                                float* __restrict__ C) {
    gemm128<true>(A, WT + (size_t)3 * 1048576, bo, C, 1.0f);
}

// ---------------------------------------------------------------------------
// Flash-style attention, double-buffered LDS, 1 sync per k-tile.
// R1: XCD-pinning swizzle; mask bias from uniform u64 (no sBias table); setprio.
// ---------------------------------------------------------------------------
#define TP 72

#if __has_builtin(__builtin_amdgcn_mfma_f32_32x32x8bf16_1k)
#define HAVE_X8 1
#endif

__global__ __launch_bounds__(256) void attn_kernel(
    const unsigned short* __restrict__ q,   // pre-scaled by log2(e)/8
    const unsigned short* __restrict__ k,
    const unsigned short* __restrict__ v,
    const int* __restrict__ key_mask,
    unsigned short* __restrict__ o) {
    __shared__ unsigned short sK[2][64 * TP];
    __shared__ unsigned short sVt[2][64 * TP];
    __shared__ unsigned long long sBits[16];

    const int t = threadIdx.x;
    const int wave = t >> 6;
    const int lane = t & 63;
    const int n31 = lane & 31;
    const int hh = lane >> 5;

    // XCD-pinning swizzle: all 8 q-tiles of a (b,h) group get the same
    // (linear_id % 8) => same XCD => K/V (256KB) fetched once into that L2.
    const int L = blockIdx.x + 8 * (blockIdx.y + 4 * blockIdx.z);  // 0..511
    const int xcd = L & 7;
    const int kk = L >> 3;                  // 0..63
    const int g = (xcd << 3) | (kk >> 3);   // (b,h) group 0..63
    const int qt = kk & 7;                  // q-tile 0..7
    const int b = g & 3;
    const int h = g >> 2;
    const int q0w = qt * 128 + wave * 32;

    const int srow = t >> 3;  // 0..31
    const int sseg = t & 7;   // 0..7

    // mask bits: bit set => masked out. Wave-uniform u64 per k-tile.
#pragma unroll
    for (int i = 0; i < 4; ++i) {
        const int idx = i * 4 + wave;
        const int sk = idx * 64 + lane;
        unsigned long long bal = __ballot(key_mask[sk * 4 + b] != 0);
        if (lane == 0) sBits[idx] = bal;
    }

    // Q fragments (B-operand of 32x32x16): B[n=lane&31][k=hh*8+j]
    bf16x8 qf[4];
    {
        const unsigned short* qrow =
            q + ((size_t)(q0w + n31) * 4 + b) * 1024 + h * 64 + hh * 8;
#pragma unroll
        for (int kc = 0; kc < 4; ++kc) {
            B8 tmp;
            tmp.s = *(const short8*)(qrow + kc * 16);
            qf[kc] = tmp.b;
        }
    }

    f32x16 O0 = {}, O1 = {}, L_ = {};
    B4 ones;
#pragma unroll
    for (int j = 0; j < 4; ++j) ones.u[j] = 0x3F80;  // bf16 1.0
#if !defined(HAVE_X8)
    B8 ones8;
#pragma unroll
    for (int j = 0; j < 8; ++j) ones8.u[j] = 0x3F80;
#endif

    const unsigned short* kbase = k + (size_t)b * 1024 + h * 64;
    const unsigned short* vbase = v + (size_t)b * 1024 + h * 64;

    // prologue: stage tile 0 into buffer 0
    {
        const unsigned short* kr = kbase + (size_t)srow * 4096 + sseg * 8;
        short8 ka = *(const short8*)kr;
        short8 kb2 = *(const short8*)(kr + (size_t)32 * 4096);
        const unsigned short* vr = vbase + (size_t)srow * 4096 + sseg * 8;
        B8 va, vb2;
        va.s = *(const short8*)vr;
        vb2.s = *(const short8*)(vr + (size_t)32 * 4096);
        *(short8*)&sK[0][srow * TP + sseg * 8] = ka;
        *(short8*)&sK[0][(32 + srow) * TP + sseg * 8] = kb2;
#pragma unroll
        for (int s = 0; s < 8; ++s) {
            const int j = (s + srow + sseg) & 7;
            sVt[0][(sseg * 8 + j) * TP + srow] = va.u[j];
            sVt[0][(sseg * 8 + j) * TP + 32 + srow] = vb2.u[j];
        }
    }

#pragma unroll 2
    for (int kt = 0; kt < 16; ++kt) {
        const int cur = kt & 1;
        __syncthreads();
        // issue next tile's global loads (completion awaited at ds_write below)
        short8 nka, nkb;
        B8 nva, nvb;
        if (kt < 15) {
            const int k0n = (kt + 1) * 64;
            const unsigned short* kr = kbase + (size_t)(k0n + srow) * 4096 + sseg * 8;
            nka = *(const short8*)kr;
            nkb = *(const short8*)(kr + (size_t)32 * 4096);
            const unsigned short* vr = vbase + (size_t)(k0n + srow) * 4096 + sseg * 8;
            nva.s = *(const short8*)vr;
            nvb.s = *(const short8*)(vr + (size_t)32 * 4096);
        }
        // --- S^T = K·Q^T with mask-bias accumulator init; exp2; pack bf16 ---
        // bias from wave-uniform bits: row = j + 8*i + 4*hh + 32*blk
        const unsigned long long bits = sBits[kt];
        const unsigned long long bsel = bits >> (hh * 4);
        B4 pfr[2][4];
#pragma unroll
        for (int blk = 0; blk < 2; ++blk) {
            const unsigned bw = (unsigned)(bsel >> (blk * 32));
            f32x16 c;
#pragma unroll
            for (int i = 0; i < 4; ++i)
#pragma unroll
                for (int j = 0; j < 4; ++j)
                    c[i * 4 + j] = ((bw >> (j + 8 * i)) & 1u) ? -16384.0f : 0.0f;
            __builtin_amdgcn_s_setprio(1);
#pragma unroll
            for (int kc = 0; kc < 4; ++kc) {
                B8 af;
                af.s = *(const short8*)&sK[cur][(blk * 32 + n31) * TP + kc * 16 + hh * 8];
                c = __builtin_amdgcn_mfma_f32_32x32x16_bf16(af.b, qf[kc], c, 0, 0, 0);
            }
            __builtin_amdgcn_s_setprio(0);
#pragma unroll
            for (int gg = 0; gg < 4; ++gg)
#pragma unroll
                for (int j = 0; j < 4; ++j)
                    pfr[blk][gg].b[j] = (__bf16)EXP2(c[gg * 4 + j]);
        }
        // --- O += P·V, l += P·1 ---
#if defined(HAVE_X8)
        __builtin_amdgcn_s_setprio(1);
#pragma unroll
        for (int blk = 0; blk < 2; ++blk) {
#pragma unroll
            for (int gg = 0; gg < 4; ++gg) {
                const int sko = blk * 32 + gg * 8 + hh * 4;
                B4 b0, b1;
                b0.s = *(const short4_*)&sVt[cur][n31 * TP + sko];
                b1.s = *(const short4_*)&sVt[cur][(32 + n31) * TP + sko];
                O0 = __builtin_amdgcn_mfma_f32_32x32x8bf16_1k(pfr[blk][gg].s, b0.s, O0, 0, 0, 0);
                O1 = __builtin_amdgcn_mfma_f32_32x32x8bf16_1k(pfr[blk][gg].s, b1.s, O1, 0, 0, 0);
                L_ = __builtin_amdgcn_mfma_f32_32x32x8bf16_1k(pfr[blk][gg].s, ones.s, L_, 0, 0, 0);
            }
        }
        __builtin_amdgcn_s_setprio(0);
#else
        __builtin_amdgcn_s_setprio(1);
#pragma unroll
        for (int blk = 0; blk < 2; ++blk) {
            B4 par[4];
#pragma unroll
            for (int gg = 0; gg < 4; ++gg) {
                par[gg].i[0] = __shfl_xor(pfr[blk][gg].i[0], 32);
                par[gg].i[1] = __shfl_xor(pfr[blk][gg].i[1], 32);
            }
#pragma unroll
            for (int w = 0; w < 2; ++w) {
                const int gsel = 2 * w + hh;
                B4 lo = (hh == 0) ? pfr[blk][gsel] : par[gsel];
                B4 hi = (hh == 0) ? par[gsel] : pfr[blk][gsel];
                B8 afr;
#pragma unroll
                for (int j = 0; j < 4; ++j) {
                    afr.u[j] = lo.u[j];
                    afr.u[4 + j] = hi.u[j];
                }
                const int sko = blk * 32 + w * 16 + hh * 8;
                B8 b0, b1;
                b0.s = *(const short8*)&sVt[cur][n31 * TP + sko];
                b1.s = *(const short8*)&sVt[cur][(32 + n31) * TP + sko];
                O0 = __builtin_amdgcn_mfma_f32_32x32x16_bf16(afr.b, b0.b, O0, 0, 0, 0);
                O1 = __builtin_amdgcn_mfma_f32_32x32x16_bf16(afr.b, b1.b, O1, 0, 0, 0);
                L_ = __builtin_amdgcn_mfma_f32_32x32x16_bf16(afr.b, ones8.b, L_, 0, 0, 0);
            }
        }
        __builtin_amdgcn_s_setprio(0);
#endif
        // --- write next tile into the other buffer (vmcnt waited here) ---
        if (kt < 15) {
            const int nb = 1 - cur;
            *(short8*)&sK[nb][srow * TP + sseg * 8] = nka;
            *(short8*)&sK[nb][(32 + srow) * TP + sseg * 8] = nkb;
#pragma unroll
            for (int s = 0; s < 8; ++s) {
                const int j = (s + srow + sseg) & 7;
                sVt[nb][(sseg * 8 + j) * TP + srow] = nva.u[j];
                sVt[nb][(sseg * 8 + j) * TP + 32 + srow] = nvb.u[j];
            }
        }
    }

    // --- epilogue: rows q=(r&3)+8*(r>>2)+4*hh; l from ones-MFMA (per-lane) ---
    unsigned short* obase = o + ((size_t)q0w * 4 + b) * 1024 + h * 64 + n31;
#pragma unroll
    for (int r = 0; r < 16; ++r) {
        const int qr = (r & 3) + 8 * (r >> 2) + 4 * hh;
        const float inv = RCP(L_[r]);
        obase[(size_t)qr * 4096] = f2bf_rne(O0[r] * inv);
        obase[(size_t)qr * 4096 + 32] = f2bf_rne(O1[r] * inv);
    }
}

extern "C" void kernel_launch(void* const* d_in, const int* in_sizes, int n_in,
                              void* d_out, int out_size, void* d_ws, size_t ws_size,
                              hipStream_t stream) {
    const float* query = (const float*)d_in[0];
    const float* key_ = (const float*)d_in[1];
    const float* value = (const float*)d_in[2];
    const int* key_mask = (const int*)d_in[3];
    const float* Wq = (const float*)d_in[4];
    const float* bq = (const float*)d_in[5];
    const float* Wk = (const float*)d_in[6];
    const float* bk = (const float*)d_in[7];
    const float* Wv = (const float*)d_in[8];
    const float* bv = (const float*)d_in[9];
    const float* Wo = (const float*)d_in[10];
    const float* bo = (const float*)d_in[11];
    float* out = (float*)d_out;

    const size_t NE = (size_t)4096 * 1024;
    unsigned short* q_ws = (unsigned short*)d_ws;
    unsigned short* k_ws = q_ws + NE;
    unsigned short* v_ws = k_ws + NE;
    unsigned short* a_ws = v_ws + NE;   // attn output; doubles as qA before attn
    unsigned short* wt_ws = a_ws + NE;  // 4 x 1M bf16 weights

    // activation bf16 scratch: qA in a_ws (dead until attn writes it);
    // kA/vA in d_out (dead until out_gemm writes it; 16MB = 2 x 8MB).
    unsigned short* qA = a_ws;
    unsigned short* kA = (unsigned short*)d_out;
    unsigned short* vA = kA + NE;

    prep<<<dim3(16, 16, 16), 256, 0, stream>>>(Wq, Wk, Wv, Wo, query, key_, value,
                                               wt_ws, qA, kA, vA);
    qkv_gemm<<<dim3(32, 8, 3), 256, 0, stream>>>(qA, kA, vA, wt_ws,
                                                 bq, bk, bv, q_ws, k_ws, v_ws);
    attn_kernel<<<dim3(8, 4, 16), 256, 0, stream>>>(q_ws, k_ws, v_ws, key_mask, a_ws);
    out_gemm<<<dim3(32, 8, 1), 256, 0, stream>>>(a_ws, wt_ws, bo, out);
}

// Round 2
// 224.498 us; speedup vs baseline: 1.1231x; 1.0854x over previous
//
#include <hip/hip_runtime.h>
#include <hip/hip_bf16.h>

// MultiHeadAttention S=1024 B=4 D=1024 H=16 DH=64
// [0] prep: Wq/Wk/Wv/Wo f32 -> bf16 B^T[n][k]  (z=0..3)
//          query/key/value f32 -> bf16 row-major (z=4..15)
// [1] qkv_gemm: m97 128x128 GEMM. p=0,1: Q/K row-major out.
//     p=2: OPERAND-SWAPPED per batch b -> writes V^T[(b,h,dh)][s] directly
//     (free transpose: A=Wv^T, Bt=vA rows strided 4, bias per-row).
// [2] attn: flash-style, dbuf LDS. R2: V staged like K (no in-kernel transpose),
//     mask bias via sBias LDS table (R1 bit-select reverted), XCD swizzle kept.
// [3] out_gemm.
// ws (bf16 elems): q @0, k @NE, vT @2NE, attn_out/qA @3NE, WT(4x1M) @4NE (40MB)

typedef __attribute__((ext_vector_type(8))) short short8;
typedef __attribute__((ext_vector_type(4))) short short4_;
typedef __attribute__((ext_vector_type(4))) float f32x4;
typedef __attribute__((ext_vector_type(16))) float f32x16;
typedef __attribute__((ext_vector_type(8))) __bf16 bf16x8;
typedef __attribute__((ext_vector_type(4))) __bf16 bf16x4;

union B8 {
    short8 s;
    bf16x8 b;
    unsigned short u[8];
};
union B4 {
    short4_ s;
    bf16x4 b;
    unsigned short u[4];
    int i[2];
};

#if __has_builtin(__builtin_amdgcn_exp2f)
#define EXP2(x) __builtin_amdgcn_exp2f(x)
#else
#define EXP2(x) exp2f(x)
#endif
#if __has_builtin(__builtin_amdgcn_rcpf)
#define RCP(x) __builtin_amdgcn_rcpf(x)
#else
#define RCP(x) (1.0f / (x))
#endif

static __device__ __forceinline__ unsigned short f2bf_rne(float f) {
    union { float f; unsigned u; } v; v.f = f;
    unsigned r = v.u + 0x7FFFu + ((v.u >> 16) & 1u);
    return (unsigned short)(r >> 16);
}

static __device__ __forceinline__ void async_lds16(const void* g, const void* l) {
    __builtin_amdgcn_global_load_lds(
        (const __attribute__((address_space(1))) unsigned int*)(unsigned long long)g,
        (__attribute__((address_space(3))) unsigned int*)(unsigned int)(unsigned long long)l,
        16, 0, 0);
}

// ---------------------------------------------------------------------------
// Prep: z<4 weight transpose+convert; z>=4 activation f32->bf16 convert.
// ---------------------------------------------------------------------------
__global__ __launch_bounds__(256) void prep(
    const float* __restrict__ Wq, const float* __restrict__ Wk,
    const float* __restrict__ Wv, const float* __restrict__ Wo,
    const float* __restrict__ query, const float* __restrict__ key,
    const float* __restrict__ value,
    unsigned short* __restrict__ WT,
    unsigned short* __restrict__ qA, unsigned short* __restrict__ kA,
    unsigned short* __restrict__ vA) {
    const int t = threadIdx.x;
    const int z = blockIdx.z;

    if (z >= 4) {
        // activation convert: 12 slices x 1M elems; 256 blocks x 4096 elems.
        const int zz = z - 4;
        const int tensor = zz >> 2;
        const int part = zz & 3;
        const float* src = (tensor == 0) ? query : (tensor == 1) ? key : value;
        unsigned short* dst = (tensor == 0) ? qA : (tensor == 1) ? kA : vA;
        const int blk = blockIdx.y * 16 + blockIdx.x;
        const size_t base = (size_t)part * 1048576 + (size_t)blk * 4096 + t * 16;
        B8 w0, w1;
#pragma unroll
        for (int i = 0; i < 2; ++i) {
            f32x4 a = *(const f32x4*)(src + base + i * 8);
            f32x4 b = *(const f32x4*)(src + base + i * 8 + 4);
#pragma unroll
            for (int j = 0; j < 4; ++j) {
                (i ? w1 : w0).u[j] = f2bf_rne(a[j]);
                (i ? w1 : w0).u[4 + j] = f2bf_rne(b[j]);
            }
        }
        *(short8*)(dst + base) = w0.s;
        *(short8*)(dst + base + 8) = w1.s;
        return;
    }

    __shared__ float sT[64][65];
    const int dtile = blockIdx.x;
    const int sub = blockIdx.y;
    const float* src;
    int spitch;
    unsigned short* dst;
    if (z < 3) {
        const float* W = (z == 0) ? Wq : (z == 1) ? Wk : Wv;
        src = W + (size_t)sub * 65536 + (size_t)dtile * 64 * 64;
        spitch = 64;
        dst = WT + (size_t)z * 1048576 + (size_t)(sub * 64) * 1024 + dtile * 64;
    } else {
        src = Wo + (size_t)dtile * 64 * 1024 + sub * 64;
        spitch = 1024;
        dst = WT + (size_t)3 * 1048576 + (size_t)(sub * 64) * 1024 + dtile * 64;
    }

    const int r = t >> 2;
    const int cseg = (t & 3) * 16;
#pragma unroll
    for (int i = 0; i < 4; ++i) {
        f32x4 v = *(const f32x4*)(src + (size_t)r * spitch + cseg + i * 4);
#pragma unroll
        for (int j = 0; j < 4; ++j) sT[r][cseg + i * 4 + j] = v[j];
    }
    __syncthreads();
    B8 w0, w1;
#pragma unroll
    for (int i = 0; i < 8; ++i) {
        w0.u[i] = f2bf_rne(sT[cseg + i][r]);
        w1.u[i] = f2bf_rne(sT[cseg + 8 + i][r]);
    }
    *(short8*)(dst + (size_t)r * 1024 + cseg) = w0.s;
    *(short8*)(dst + (size_t)r * 1024 + cseg + 8) = w1.s;
}

// ---------------------------------------------------------------------------
// 128x128-tile GEMM (BK=64), both operands bf16 via global_load_lds (m97 shape).
// Generalized: runtime row/col pitches, bias per-row or per-col.
// ---------------------------------------------------------------------------
template <bool OUT_F32, bool BIAS_ROW>
__device__ __forceinline__ void gemm128(const unsigned short* __restrict__ A,
                                        size_t lda,
                                        const unsigned short* __restrict__ Bt,
                                        size_t ldb,
                                        const float* __restrict__ bias,
                                        void* __restrict__ Cv, size_t ldc,
                                        float oscale, int row0, int col0) {
    __shared__ unsigned short sA[128 * 64];
    __shared__ unsigned short sB[128 * 64];
    const int t = threadIdx.x;
    const int w = t >> 6;
    const int lane = t & 63;
    const int quad = lane >> 4;
    const int l15 = lane & 15;
    const int wr = w >> 1;
    const int wc = w & 1;
    const int lrow8 = lane >> 3;
    const int lseg = lane & 7;

    f32x4 acc[4][4] = {};

    for (int k0 = 0; k0 < 1024; k0 += 64) {
#pragma unroll
        for (int i = 0; i < 4; ++i) {
            const int rr = w * 32 + i * 8;
            async_lds16(A + (size_t)(row0 + rr + lrow8) * lda + k0 + lseg * 8,
                        &sA[rr * 64]);
            async_lds16(Bt + (size_t)(col0 + rr + lrow8) * ldb + k0 + lseg * 8,
                        &sB[rr * 64]);
        }
        __syncthreads();
#pragma unroll
        for (int kf = 0; kf < 2; ++kf) {
            B8 af[4], bf[4];
#pragma unroll
            for (int i = 0; i < 4; ++i)
                af[i].s = *(const short8*)&sA[(wr * 64 + i * 16 + l15) * 64 + kf * 32 + quad * 8];
#pragma unroll
            for (int j = 0; j < 4; ++j)
                bf[j].s = *(const short8*)&sB[(wc * 64 + j * 16 + l15) * 64 + kf * 32 + quad * 8];
#pragma unroll
            for (int i = 0; i < 4; ++i)
#pragma unroll
                for (int j = 0; j < 4; ++j)
                    acc[i][j] = __builtin_amdgcn_mfma_f32_16x16x32_bf16(af[i].b, bf[j].b,
                                                                        acc[i][j], 0, 0, 0);
        }
        __syncthreads();
    }
    float brow[4][4];
    if constexpr (BIAS_ROW) {
#pragma unroll
        for (int i = 0; i < 4; ++i)
#pragma unroll
            for (int r = 0; r < 4; ++r)
                brow[i][r] = bias[row0 + wr * 64 + i * 16 + quad * 4 + r];
    }
#pragma unroll
    for (int j = 0; j < 4; ++j) {
        const int col = col0 + wc * 64 + j * 16 + l15;
        const float bcol = BIAS_ROW ? 0.0f : bias[col];
#pragma unroll
        for (int i = 0; i < 4; ++i) {
#pragma unroll
            for (int r = 0; r < 4; ++r) {
                const int row = row0 + wr * 64 + i * 16 + quad * 4 + r;
                const size_t idx = (size_t)row * ldc + col;
                const float bb = BIAS_ROW ? brow[i][r] : bcol;
                const float val = (acc[i][j][r] + bb) * oscale;
                if constexpr (OUT_F32)
                    ((float*)Cv)[idx] = val;
                else
                    ((unsigned short*)Cv)[idx] = f2bf_rne(val);
            }
        }
    }
}

#define SCALE_L2E 0.18033688011112042f  // (1/8) * log2(e)

__global__ __launch_bounds__(256) void qkv_gemm(
    const unsigned short* __restrict__ qA, const unsigned short* __restrict__ kA,
    const unsigned short* __restrict__ vA,
    const unsigned short* __restrict__ WT,
    const float* __restrict__ bq, const float* __restrict__ bk, const float* __restrict__ bv,
    unsigned short* q_o, unsigned short* k_o, unsigned short* vT_o) {
    const int p = blockIdx.z;
    if (p < 2) {
        const unsigned short* A = (p == 0) ? qA : kA;
        const unsigned short* Bt = WT + (size_t)p * 1048576;
        const float* bias = (p == 0) ? bq : bk;
        unsigned short* C = (p == 0) ? q_o : k_o;
        const float osc = (p == 0) ? SCALE_L2E : 1.0f;  // pre-scale q for attn exp2
        gemm128<false, false>(A, 1024, Bt, 1024, bias, C, 1024, osc,
                              blockIdx.x * 128, blockIdx.y * 128);
    } else {
        // V^T: per batch b, C[colV][s] = sum_d Wv^T[colV][d] * vA[(s*4+b)][d]
        // A = Wv^T (WT slot 2), Bt = vA rows strided 4 (ldb=4096), bias per-row.
        const int b = blockIdx.x >> 3;
        const int rt = blockIdx.x & 7;
        gemm128<false, true>(WT + (size_t)2 * 1048576, 1024,
                             vA + (size_t)b * 1024, 4096, bv,
                             vT_o + (size_t)b * 1048576, 1024, 1.0f,
                             rt * 128, blockIdx.y * 128);
    }
}

__global__ __launch_bounds__(256) void out_gemm(const unsigned short* __restrict__ A,
                                                const unsigned short* __restrict__ WT,
                                                const float* __restrict__ bo,
                                                float* __restrict__ C) {
    gemm128<true, false>(A, 1024, WT + (size_t)3 * 1048576, 1024, bo, C, 1024, 1.0f,
                         blockIdx.x * 128, blockIdx.y * 128);
}

// ---------------------------------------------------------------------------
// Flash-style attention, double-buffered LDS, 1 sync per k-tile.
// R2: V comes in pre-transposed (vT[(b,h,dh)][s]) -> staged exactly like K.
//     Mask bias via sBias LDS table. XCD-pinning swizzle + setprio kept.
// ---------------------------------------------------------------------------
#define TP 72

#if __has_builtin(__builtin_amdgcn_mfma_f32_32x32x8bf16_1k)
#define HAVE_X8 1
#endif

__global__ __launch_bounds__(256) void attn_kernel(
    const unsigned short* __restrict__ q,   // pre-scaled by log2(e)/8
    const unsigned short* __restrict__ k,
    const unsigned short* __restrict__ vT,  // [(b*16+h)*64+dh][s]
    const int* __restrict__ key_mask,
    unsigned short* __restrict__ o) {
    __shared__ unsigned short sK[2][64 * TP];
    __shared__ unsigned short sVt[2][64 * TP];
    __shared__ float sBias[1024];  // [kt][blk][hh][r]
    __shared__ unsigned long long sBits[16];

    const int t = threadIdx.x;
    const int wave = t >> 6;
    const int lane = t & 63;
    const int n31 = lane & 31;
    const int hh = lane >> 5;

    // XCD-pinning swizzle: all 8 q-tiles of a (b,h) group get the same
    // (linear_id % 8) => same XCD => K/V (512KB) fetched once into that L2.
    const int L = blockIdx.x + 8 * (blockIdx.y + 4 * blockIdx.z);  // 0..511
    const int xcd = L & 7;
    const int kk = L >> 3;                  // 0..63
    const int g = (xcd << 3) | (kk >> 3);   // (b,h) group 0..63
    const int qt = kk & 7;                  // q-tile 0..7
    const int b = g & 3;
    const int h = g >> 2;
    const int q0w = qt * 128 + wave * 32;

    const int srow = t >> 3;  // 0..31
    const int sseg = t & 7;   // 0..7

    // mask bits: bit set => masked out
#pragma unroll
    for (int i = 0; i < 4; ++i) {
        const int idx = i * 4 + wave;
        const int sk = idx * 64 + lane;
        unsigned long long bal = __ballot(key_mask[sk * 4 + b] != 0);
        if (lane == 0) sBits[idx] = bal;
    }
    __syncthreads();
    // accumulator-init bias table: -16384 => exp2 underflow => exact 0
#pragma unroll
    for (int i = 0; i < 4; ++i) {
        const int idx = t * 4 + i;  // 0..1023 = [kt][blk][hh][r]
        const int r = idx & 15;
        const int hb = (idx >> 4) & 1;
        const int blk = (idx >> 5) & 1;
        const int kt = idx >> 6;
        const int row = (r & 3) + 8 * (r >> 2) + 4 * hb + blk * 32;
        sBias[idx] = ((sBits[kt] >> row) & 1ull) ? -16384.0f : 0.0f;
    }

    // Q fragments (B-operand of 32x32x16): B[n=lane&31][k=hh*8+j]
    bf16x8 qf[4];
    {
        const unsigned short* qrow =
            q + ((size_t)(q0w + n31) * 4 + b) * 1024 + h * 64 + hh * 8;
#pragma unroll
        for (int kc = 0; kc < 4; ++kc) {
            B8 tmp;
            tmp.s = *(const short8*)(qrow + kc * 16);
            qf[kc] = tmp.b;
        }
    }

    f32x16 O0 = {}, O1 = {}, L_ = {};
    B4 ones;
#pragma unroll
    for (int j = 0; j < 4; ++j) ones.u[j] = 0x3F80;  // bf16 1.0
#if !defined(HAVE_X8)
    B8 ones8;
#pragma unroll
    for (int j = 0; j < 8; ++j) ones8.u[j] = 0x3F80;
#endif

    const unsigned short* kbase = k + (size_t)b * 1024 + h * 64;
    const unsigned short* vtb = vT + ((size_t)(b * 16 + h) * 64) * 1024;

    // prologue: stage tile 0 into buffer 0 (V staged like K: rows = dh)
    {
        const unsigned short* kr = kbase + (size_t)srow * 4096 + sseg * 8;
        short8 ka = *(const short8*)kr;
        short8 kb2 = *(const short8*)(kr + (size_t)32 * 4096);
        const unsigned short* vr = vtb + (size_t)srow * 1024 + sseg * 8;
        short8 va = *(const short8*)vr;
        short8 vb2 = *(const short8*)(vr + (size_t)32 * 1024);
        *(short8*)&sK[0][srow * TP + sseg * 8] = ka;
        *(short8*)&sK[0][(32 + srow) * TP + sseg * 8] = kb2;
        *(short8*)&sVt[0][srow * TP + sseg * 8] = va;
        *(short8*)&sVt[0][(32 + srow) * TP + sseg * 8] = vb2;
    }

#pragma unroll 2
    for (int kt = 0; kt < 16; ++kt) {
        const int cur = kt & 1;
        __syncthreads();
        // issue next tile's global loads (completion awaited at ds_write below)
        short8 nka, nkb, nva, nvb;
        if (kt < 15) {
            const int k0n = (kt + 1) * 64;
            const unsigned short* kr = kbase + (size_t)(k0n + srow) * 4096 + sseg * 8;
            nka = *(const short8*)kr;
            nkb = *(const short8*)(kr + (size_t)32 * 4096);
            const unsigned short* vr = vtb + (size_t)srow * 1024 + k0n + sseg * 8;
            nva = *(const short8*)vr;
            nvb = *(const short8*)(vr + (size_t)32 * 1024);
        }
        // --- S^T = K·Q^T with mask-bias accumulator init; exp2; pack bf16 ---
        B4 pfr[2][4];
#pragma unroll
        for (int blk = 0; blk < 2; ++blk) {
            f32x16 c;
            const f32x4* bp = (const f32x4*)&sBias[((kt * 2 + blk) * 2 + hh) * 16];
#pragma unroll
            for (int i = 0; i < 4; ++i) {
                f32x4 x = bp[i];
#pragma unroll
                for (int j = 0; j < 4; ++j) c[i * 4 + j] = x[j];
            }
            __builtin_amdgcn_s_setprio(1);
#pragma unroll
            for (int kc = 0; kc < 4; ++kc) {
                B8 af;
                af.s = *(const short8*)&sK[cur][(blk * 32 + n31) * TP + kc * 16 + hh * 8];
                c = __builtin_amdgcn_mfma_f32_32x32x16_bf16(af.b, qf[kc], c, 0, 0, 0);
            }
            __builtin_amdgcn_s_setprio(0);
#pragma unroll
            for (int gg = 0; gg < 4; ++gg)
#pragma unroll
                for (int j = 0; j < 4; ++j)
                    pfr[blk][gg].b[j] = (__bf16)EXP2(c[gg * 4 + j]);
        }
        // --- O += P·V, l += P·1 ---
#if defined(HAVE_X8)
        __builtin_amdgcn_s_setprio(1);
#pragma unroll
        for (int blk = 0; blk < 2; ++blk) {
#pragma unroll
            for (int gg = 0; gg < 4; ++gg) {
                const int sko = blk * 32 + gg * 8 + hh * 4;
                B4 b0, b1;
                b0.s = *(const short4_*)&sVt[cur][n31 * TP + sko];
                b1.s = *(const short4_*)&sVt[cur][(32 + n31) * TP + sko];
                O0 = __builtin_amdgcn_mfma_f32_32x32x8bf16_1k(pfr[blk][gg].s, b0.s, O0, 0, 0, 0);
                O1 = __builtin_amdgcn_mfma_f32_32x32x8bf16_1k(pfr[blk][gg].s, b1.s, O1, 0, 0, 0);
                L_ = __builtin_amdgcn_mfma_f32_32x32x8bf16_1k(pfr[blk][gg].s, ones.s, L_, 0, 0, 0);
            }
        }
        __builtin_amdgcn_s_setprio(0);
#else
        __builtin_amdgcn_s_setprio(1);
#pragma unroll
        for (int blk = 0; blk < 2; ++blk) {
            B4 par[4];
#pragma unroll
            for (int gg = 0; gg < 4; ++gg) {
                par[gg].i[0] = __shfl_xor(pfr[blk][gg].i[0], 32);
                par[gg].i[1] = __shfl_xor(pfr[blk][gg].i[1], 32);
            }
#pragma unroll
            for (int w = 0; w < 2; ++w) {
                const int gsel = 2 * w + hh;
                B4 lo = (hh == 0) ? pfr[blk][gsel] : par[gsel];
                B4 hi = (hh == 0) ? par[gsel] : pfr[blk][gsel];
                B8 afr;
#pragma unroll
                for (int j = 0; j < 4; ++j) {
                    afr.u[j] = lo.u[j];
                    afr.u[4 + j] = hi.u[j];
                }
                const int sko = blk * 32 + w * 16 + hh * 8;
                B8 b0, b1;
                b0.s = *(const short8*)&sVt[cur][n31 * TP + sko];
                b1.s = *(const short8*)&sVt[cur][(32 + n31) * TP + sko];
                O0 = __builtin_amdgcn_mfma_f32_32x32x16_bf16(afr.b, b0.b, O0, 0, 0, 0);
                O1 = __builtin_amdgcn_mfma_f32_32x32x16_bf16(afr.b, b1.b, O1, 0, 0, 0);
                L_ = __builtin_amdgcn_mfma_f32_32x32x16_bf16(afr.b, ones8.b, L_, 0, 0, 0);
            }
        }
        __builtin_amdgcn_s_setprio(0);
#endif
        // --- write next tile into the other buffer (vmcnt waited here) ---
        if (kt < 15) {
            const int nb = 1 - cur;
            *(short8*)&sK[nb][srow * TP + sseg * 8] = nka;
            *(short8*)&sK[nb][(32 + srow) * TP + sseg * 8] = nkb;
            *(short8*)&sVt[nb][srow * TP + sseg * 8] = nva;
            *(short8*)&sVt[nb][(32 + srow) * TP + sseg * 8] = nvb;
        }
    }

    // --- epilogue: rows q=(r&3)+8*(r>>2)+4*hh; l from ones-MFMA (per-lane) ---
    unsigned short* obase = o + ((size_t)q0w * 4 + b) * 1024 + h * 64 + n31;
#pragma unroll
    for (int r = 0; r < 16; ++r) {
        const int qr = (r & 3) + 8 * (r >> 2) + 4 * hh;
        const float inv = RCP(L_[r]);
        obase[(size_t)qr * 4096] = f2bf_rne(O0[r] * inv);
        obase[(size_t)qr * 4096 + 32] = f2bf_rne(O1[r] * inv);
    }
}

extern "C" void kernel_launch(void* const* d_in, const int* in_sizes, int n_in,
                              void* d_out, int out_size, void* d_ws, size_t ws_size,
                              hipStream_t stream) {
    const float* query = (const float*)d_in[0];
    const float* key_ = (const float*)d_in[1];
    const float* value = (const float*)d_in[2];
    const int* key_mask = (const int*)d_in[3];
    const float* Wq = (const float*)d_in[4];
    const float* bq = (const float*)d_in[5];
    const float* Wk = (const float*)d_in[6];
    const float* bk = (const float*)d_in[7];
    const float* Wv = (const float*)d_in[8];
    const float* bv = (const float*)d_in[9];
    const float* Wo = (const float*)d_in[10];
    const float* bo = (const float*)d_in[11];
    float* out = (float*)d_out;

    const size_t NE = (size_t)4096 * 1024;
    unsigned short* q_ws = (unsigned short*)d_ws;
    unsigned short* k_ws = q_ws + NE;
    unsigned short* v_ws = k_ws + NE;   // holds V^T [(b,h,dh)][s]
    unsigned short* a_ws = v_ws + NE;   // attn output; doubles as qA before attn
    unsigned short* wt_ws = a_ws + NE;  // 4 x 1M bf16 weights

    // activation bf16 scratch: qA in a_ws (dead until attn writes it);
    // kA/vA in d_out (dead until out_gemm writes it; 16MB = 2 x 8MB).
    unsigned short* qA = a_ws;
    unsigned short* kA = (unsigned short*)d_out;
    unsigned short* vA = kA + NE;

    prep<<<dim3(16, 16, 16), 256, 0, stream>>>(Wq, Wk, Wv, Wo, query, key_, value,
                                               wt_ws, qA, kA, vA);
    qkv_gemm<<<dim3(32, 8, 3), 256, 0, stream>>>(qA, kA, vA, wt_ws,
                                                 bq, bk, bv, q_ws, k_ws, v_ws);
    attn_kernel<<<dim3(8, 4, 16), 256, 0, stream>>>(q_ws, k_ws, v_ws, key_mask, a_ws);
    out_gemm<<<dim3(32, 8, 1), 256, 0, stream>>>(a_ws, wt_ws, bo, out);
}

// Round 3
// 216.610 us; speedup vs baseline: 1.1640x; 1.0364x over previous
//
#include <hip/hip_runtime.h>
#include <hip/hip_bf16.h>

// MultiHeadAttention S=1024 B=4 D=1024 H=16 DH=64
// [0] prep: Wq/Wk/Wv/Wo f32 -> bf16 B^T[n][k]  (z=0..3)
//          query/key/value f32 -> bf16 row-major (z=4..15)
// [1] qkv_gemm: m97 128x128 GEMM. p=0,1: Q/K row-major out.
//     p=2: OPERAND-SWAPPED per batch b -> writes V^T[(b,h,dh)][s] directly.
//     R3: single shared sA/sB for both instantiations (64KB->32KB, 2->4 blk/CU);
//         both-sides XOR bank swizzle (pre-swizzled global src + swizzled read).
// [2] attn: flash-style, dbuf LDS, V pre-transposed, sBias table, XCD swizzle.
// [3] out_gemm (same gemm128, same swizzle).
// ws (bf16 elems): q @0, k @NE, vT @2NE, attn_out/qA @3NE, WT(4x1M) @4NE (40MB)

typedef __attribute__((ext_vector_type(8))) short short8;
typedef __attribute__((ext_vector_type(4))) short short4_;
typedef __attribute__((ext_vector_type(4))) float f32x4;
typedef __attribute__((ext_vector_type(16))) float f32x16;
typedef __attribute__((ext_vector_type(8))) __bf16 bf16x8;
typedef __attribute__((ext_vector_type(4))) __bf16 bf16x4;

union B8 {
    short8 s;
    bf16x8 b;
    unsigned short u[8];
};
union B4 {
    short4_ s;
    bf16x4 b;
    unsigned short u[4];
    int i[2];
};

#if __has_builtin(__builtin_amdgcn_exp2f)
#define EXP2(x) __builtin_amdgcn_exp2f(x)
#else
#define EXP2(x) exp2f(x)
#endif
#if __has_builtin(__builtin_amdgcn_rcpf)
#define RCP(x) __builtin_amdgcn_rcpf(x)
#else
#define RCP(x) (1.0f / (x))
#endif

static __device__ __forceinline__ unsigned short f2bf_rne(float f) {
    union { float f; unsigned u; } v; v.f = f;
    unsigned r = v.u + 0x7FFFu + ((v.u >> 16) & 1u);
    return (unsigned short)(r >> 16);
}

static __device__ __forceinline__ void async_lds16(const void* g, const void* l) {
    __builtin_amdgcn_global_load_lds(
        (const __attribute__((address_space(1))) unsigned int*)(unsigned long long)g,
        (__attribute__((address_space(3))) unsigned int*)(unsigned int)(unsigned long long)l,
        16, 0, 0);
}

// ---------------------------------------------------------------------------
// Prep: z<4 weight transpose+convert; z>=4 activation f32->bf16 convert.
// ---------------------------------------------------------------------------
__global__ __launch_bounds__(256) void prep(
    const float* __restrict__ Wq, const float* __restrict__ Wk,
    const float* __restrict__ Wv, const float* __restrict__ Wo,
    const float* __restrict__ query, const float* __restrict__ key,
    const float* __restrict__ value,
    unsigned short* __restrict__ WT,
    unsigned short* __restrict__ qA, unsigned short* __restrict__ kA,
    unsigned short* __restrict__ vA) {
    const int t = threadIdx.x;
    const int z = blockIdx.z;

    if (z >= 4) {
        // activation convert: 12 slices x 1M elems; 256 blocks x 4096 elems.
        const int zz = z - 4;
        const int tensor = zz >> 2;
        const int part = zz & 3;
        const float* src = (tensor == 0) ? query : (tensor == 1) ? key : value;
        unsigned short* dst = (tensor == 0) ? qA : (tensor == 1) ? kA : vA;
        const int blk = blockIdx.y * 16 + blockIdx.x;
        const size_t base = (size_t)part * 1048576 + (size_t)blk * 4096 + t * 16;
        B8 w0, w1;
#pragma unroll
        for (int i = 0; i < 2; ++i) {
            f32x4 a = *(const f32x4*)(src + base + i * 8);
            f32x4 b = *(const f32x4*)(src + base + i * 8 + 4);
#pragma unroll
            for (int j = 0; j < 4; ++j) {
                (i ? w1 : w0).u[j] = f2bf_rne(a[j]);
                (i ? w1 : w0).u[4 + j] = f2bf_rne(b[j]);
            }
        }
        *(short8*)(dst + base) = w0.s;
        *(short8*)(dst + base + 8) = w1.s;
        return;
    }

    __shared__ float sT[64][65];
    const int dtile = blockIdx.x;
    const int sub = blockIdx.y;
    const float* src;
    int spitch;
    unsigned short* dst;
    if (z < 3) {
        const float* W = (z == 0) ? Wq : (z == 1) ? Wk : Wv;
        src = W + (size_t)sub * 65536 + (size_t)dtile * 64 * 64;
        spitch = 64;
        dst = WT + (size_t)z * 1048576 + (size_t)(sub * 64) * 1024 + dtile * 64;
    } else {
        src = Wo + (size_t)dtile * 64 * 1024 + sub * 64;
        spitch = 1024;
        dst = WT + (size_t)3 * 1048576 + (size_t)(sub * 64) * 1024 + dtile * 64;
    }

    const int r = t >> 2;
    const int cseg = (t & 3) * 16;
#pragma unroll
    for (int i = 0; i < 4; ++i) {
        f32x4 v = *(const f32x4*)(src + (size_t)r * spitch + cseg + i * 4);
#pragma unroll
        for (int j = 0; j < 4; ++j) sT[r][cseg + i * 4 + j] = v[j];
    }
    __syncthreads();
    B8 w0, w1;
#pragma unroll
    for (int i = 0; i < 8; ++i) {
        w0.u[i] = f2bf_rne(sT[cseg + i][r]);
        w1.u[i] = f2bf_rne(sT[cseg + 8 + i][r]);
    }
    *(short8*)(dst + (size_t)r * 1024 + cseg) = w0.s;
    *(short8*)(dst + (size_t)r * 1024 + cseg + 8) = w1.s;
}

// ---------------------------------------------------------------------------
// 128x128-tile GEMM (BK=64), both operands bf16 via global_load_lds (m97 shape).
// Shared buffers passed in (single allocation per kernel regardless of
// instantiation count). Both-sides XOR swizzle: global source column segment
// is lseg^lrow8 (stripe base is 0 mod 8 rows), read column is (c)^(row&7).
// After swizzle each quad-group's 16 lanes cover all 8 bank granules (2-way).
// ---------------------------------------------------------------------------
template <bool OUT_F32, bool BIAS_ROW>
__device__ __forceinline__ void gemm128(unsigned short* __restrict__ sA,
                                        unsigned short* __restrict__ sB,
                                        const unsigned short* __restrict__ A,
                                        size_t lda,
                                        const unsigned short* __restrict__ Bt,
                                        size_t ldb,
                                        const float* __restrict__ bias,
                                        void* __restrict__ Cv, size_t ldc,
                                        float oscale, int row0, int col0) {
    const int t = threadIdx.x;
    const int w = t >> 6;
    const int lane = t & 63;
    const int quad = lane >> 4;
    const int l15 = lane & 15;
    const int l7 = l15 & 7;
    const int wr = w >> 1;
    const int wc = w & 1;
    const int lrow8 = lane >> 3;
    const int lseg = lane & 7;
    const int gseg = lseg ^ lrow8;  // pre-swizzled global column segment

    f32x4 acc[4][4] = {};

    for (int k0 = 0; k0 < 1024; k0 += 64) {
#pragma unroll
        for (int i = 0; i < 4; ++i) {
            const int rr = w * 32 + i * 8;
            async_lds16(A + (size_t)(row0 + rr + lrow8) * lda + k0 + gseg * 8,
                        &sA[rr * 64]);
            async_lds16(Bt + (size_t)(col0 + rr + lrow8) * ldb + k0 + gseg * 8,
                        &sB[rr * 64]);
        }
        __syncthreads();
#pragma unroll
        for (int kf = 0; kf < 2; ++kf) {
            B8 af[4], bf[4];
#pragma unroll
            for (int i = 0; i < 4; ++i)
                af[i].s = *(const short8*)&sA[(wr * 64 + i * 16 + l15) * 64 +
                                              ((kf * 4 + quad) ^ l7) * 8];
#pragma unroll
            for (int j = 0; j < 4; ++j)
                bf[j].s = *(const short8*)&sB[(wc * 64 + j * 16 + l15) * 64 +
                                              ((kf * 4 + quad) ^ l7) * 8];
#pragma unroll
            for (int i = 0; i < 4; ++i)
#pragma unroll
                for (int j = 0; j < 4; ++j)
                    acc[i][j] = __builtin_amdgcn_mfma_f32_16x16x32_bf16(af[i].b, bf[j].b,
                                                                        acc[i][j], 0, 0, 0);
        }
        __syncthreads();
    }
    float brow[4][4];
    if constexpr (BIAS_ROW) {
#pragma unroll
        for (int i = 0; i < 4; ++i)
#pragma unroll
            for (int r = 0; r < 4; ++r)
                brow[i][r] = bias[row0 + wr * 64 + i * 16 + quad * 4 + r];
    }
#pragma unroll
    for (int j = 0; j < 4; ++j) {
        const int col = col0 + wc * 64 + j * 16 + l15;
        const float bcol = BIAS_ROW ? 0.0f : bias[col];
#pragma unroll
        for (int i = 0; i < 4; ++i) {
#pragma unroll
            for (int r = 0; r < 4; ++r) {
                const int row = row0 + wr * 64 + i * 16 + quad * 4 + r;
                const size_t idx = (size_t)row * ldc + col;
                const float bb = BIAS_ROW ? brow[i][r] : bcol;
                const float val = (acc[i][j][r] + bb) * oscale;
                if constexpr (OUT_F32)
                    ((float*)Cv)[idx] = val;
                else
                    ((unsigned short*)Cv)[idx] = f2bf_rne(val);
            }
        }
    }
}

#define SCALE_L2E 0.18033688011112042f  // (1/8) * log2(e)

__global__ __launch_bounds__(256) void qkv_gemm(
    const unsigned short* __restrict__ qA, const unsigned short* __restrict__ kA,
    const unsigned short* __restrict__ vA,
    const unsigned short* __restrict__ WT,
    const float* __restrict__ bq, const float* __restrict__ bk, const float* __restrict__ bv,
    unsigned short* q_o, unsigned short* k_o, unsigned short* vT_o) {
    __shared__ unsigned short sA[128 * 64];
    __shared__ unsigned short sB[128 * 64];
    const int p = blockIdx.z;
    if (p < 2) {
        const unsigned short* A = (p == 0) ? qA : kA;
        const unsigned short* Bt = WT + (size_t)p * 1048576;
        const float* bias = (p == 0) ? bq : bk;
        unsigned short* C = (p == 0) ? q_o : k_o;
        const float osc = (p == 0) ? SCALE_L2E : 1.0f;  // pre-scale q for attn exp2
        gemm128<false, false>(sA, sB, A, 1024, Bt, 1024, bias, C, 1024, osc,
                              blockIdx.x * 128, blockIdx.y * 128);
    } else {
        // V^T: per batch b, C[colV][s] = sum_d Wv^T[colV][d] * vA[(s*4+b)][d]
        // A = Wv^T (WT slot 2), Bt = vA rows strided 4 (ldb=4096), bias per-row.
        const int b = blockIdx.x >> 3;
        const int rt = blockIdx.x & 7;
        gemm128<false, true>(sA, sB, WT + (size_t)2 * 1048576, 1024,
                             vA + (size_t)b * 1024, 4096, bv,
                             vT_o + (size_t)b * 1048576, 1024, 1.0f,
                             rt * 128, blockIdx.y * 128);
    }
}

__global__ __launch_bounds__(256) void out_gemm(const unsigned short* __restrict__ A,
                                                const unsigned short* __restrict__ WT,
                                                const float* __restrict__ bo,
                                                float* __restrict__ C) {
    __shared__ unsigned short sA[128 * 64];
    __shared__ unsigned short sB[128 * 64];
    gemm128<true, false>(sA, sB, A, 1024, WT + (size_t)3 * 1048576, 1024, bo, C, 1024,
                         1.0f, blockIdx.x * 128, blockIdx.y * 128);
}

// ---------------------------------------------------------------------------
// Flash-style attention, double-buffered LDS, 1 sync per k-tile.
// V comes in pre-transposed (vT[(b,h,dh)][s]) -> staged exactly like K.
// Mask bias via sBias LDS table. XCD-pinning swizzle + setprio.
// ---------------------------------------------------------------------------
#define TP 72

#if __has_builtin(__builtin_amdgcn_mfma_f32_32x32x8bf16_1k)
#define HAVE_X8 1
#endif

__global__ __launch_bounds__(256) void attn_kernel(
    const unsigned short* __restrict__ q,   // pre-scaled by log2(e)/8
    const unsigned short* __restrict__ k,
    const unsigned short* __restrict__ vT,  // [(b*16+h)*64+dh][s]
    const int* __restrict__ key_mask,
    unsigned short* __restrict__ o) {
    __shared__ unsigned short sK[2][64 * TP];
    __shared__ unsigned short sVt[2][64 * TP];
    __shared__ float sBias[1024];  // [kt][blk][hh][r]
    __shared__ unsigned long long sBits[16];

    const int t = threadIdx.x;
    const int wave = t >> 6;
    const int lane = t & 63;
    const int n31 = lane & 31;
    const int hh = lane >> 5;

    // XCD-pinning swizzle: all 8 q-tiles of a (b,h) group get the same
    // (linear_id % 8) => same XCD => K/V (512KB) fetched once into that L2.
    const int L = blockIdx.x + 8 * (blockIdx.y + 4 * blockIdx.z);  // 0..511
    const int xcd = L & 7;
    const int kk = L >> 3;                  // 0..63
    const int g = (xcd << 3) | (kk >> 3);   // (b,h) group 0..63
    const int qt = kk & 7;                  // q-tile 0..7
    const int b = g & 3;
    const int h = g >> 2;
    const int q0w = qt * 128 + wave * 32;

    const int srow = t >> 3;  // 0..31
    const int sseg = t & 7;   // 0..7

    // mask bits: bit set => masked out
#pragma unroll
    for (int i = 0; i < 4; ++i) {
        const int idx = i * 4 + wave;
        const int sk = idx * 64 + lane;
        unsigned long long bal = __ballot(key_mask[sk * 4 + b] != 0);
        if (lane == 0) sBits[idx] = bal;
    }
    __syncthreads();
    // accumulator-init bias table: -16384 => exp2 underflow => exact 0
#pragma unroll
    for (int i = 0; i < 4; ++i) {
        const int idx = t * 4 + i;  // 0..1023 = [kt][blk][hh][r]
        const int r = idx & 15;
        const int hb = (idx >> 4) & 1;
        const int blk = (idx >> 5) & 1;
        const int kt = idx >> 6;
        const int row = (r & 3) + 8 * (r >> 2) + 4 * hb + blk * 32;
        sBias[idx] = ((sBits[kt] >> row) & 1ull) ? -16384.0f : 0.0f;
    }

    // Q fragments (B-operand of 32x32x16): B[n=lane&31][k=hh*8+j]
    bf16x8 qf[4];
    {
        const unsigned short* qrow =
            q + ((size_t)(q0w + n31) * 4 + b) * 1024 + h * 64 + hh * 8;
#pragma unroll
        for (int kc = 0; kc < 4; ++kc) {
            B8 tmp;
            tmp.s = *(const short8*)(qrow + kc * 16);
            qf[kc] = tmp.b;
        }
    }

    f32x16 O0 = {}, O1 = {}, L_ = {};
    B4 ones;
#pragma unroll
    for (int j = 0; j < 4; ++j) ones.u[j] = 0x3F80;  // bf16 1.0
#if !defined(HAVE_X8)
    B8 ones8;
#pragma unroll
    for (int j = 0; j < 8; ++j) ones8.u[j] = 0x3F80;
#endif

    const unsigned short* kbase = k + (size_t)b * 1024 + h * 64;
    const unsigned short* vtb = vT + ((size_t)(b * 16 + h) * 64) * 1024;

    // prologue: stage tile 0 into buffer 0 (V staged like K: rows = dh)
    {
        const unsigned short* kr = kbase + (size_t)srow * 4096 + sseg * 8;
        short8 ka = *(const short8*)kr;
        short8 kb2 = *(const short8*)(kr + (size_t)32 * 4096);
        const unsigned short* vr = vtb + (size_t)srow * 1024 + sseg * 8;
        short8 va = *(const short8*)vr;
        short8 vb2 = *(const short8*)(vr + (size_t)32 * 1024);
        *(short8*)&sK[0][srow * TP + sseg * 8] = ka;
        *(short8*)&sK[0][(32 + srow) * TP + sseg * 8] = kb2;
        *(short8*)&sVt[0][srow * TP + sseg * 8] = va;
        *(short8*)&sVt[0][(32 + srow) * TP + sseg * 8] = vb2;
    }

#pragma unroll 2
    for (int kt = 0; kt < 16; ++kt) {
        const int cur = kt & 1;
        __syncthreads();
        // issue next tile's global loads (completion awaited at ds_write below)
        short8 nka, nkb, nva, nvb;
        if (kt < 15) {
            const int k0n = (kt + 1) * 64;
            const unsigned short* kr = kbase + (size_t)(k0n + srow) * 4096 + sseg * 8;
            nka = *(const short8*)kr;
            nkb = *(const short8*)(kr + (size_t)32 * 4096);
            const unsigned short* vr = vtb + (size_t)srow * 1024 + k0n + sseg * 8;
            nva = *(const short8*)vr;
            nvb = *(const short8*)(vr + (size_t)32 * 1024);
        }
        // --- S^T = K·Q^T with mask-bias accumulator init; exp2; pack bf16 ---
        B4 pfr[2][4];
#pragma unroll
        for (int blk = 0; blk < 2; ++blk) {
            f32x16 c;
            const f32x4* bp = (const f32x4*)&sBias[((kt * 2 + blk) * 2 + hh) * 16];
#pragma unroll
            for (int i = 0; i < 4; ++i) {
                f32x4 x = bp[i];
#pragma unroll
                for (int j = 0; j < 4; ++j) c[i * 4 + j] = x[j];
            }
            __builtin_amdgcn_s_setprio(1);
#pragma unroll
            for (int kc = 0; kc < 4; ++kc) {
                B8 af;
                af.s = *(const short8*)&sK[cur][(blk * 32 + n31) * TP + kc * 16 + hh * 8];
                c = __builtin_amdgcn_mfma_f32_32x32x16_bf16(af.b, qf[kc], c, 0, 0, 0);
            }
            __builtin_amdgcn_s_setprio(0);
#pragma unroll
            for (int gg = 0; gg < 4; ++gg)
#pragma unroll
                for (int j = 0; j < 4; ++j)
                    pfr[blk][gg].b[j] = (__bf16)EXP2(c[gg * 4 + j]);
        }
        // --- O += P·V, l += P·1 ---
#if defined(HAVE_X8)
        __builtin_amdgcn_s_setprio(1);
#pragma unroll
        for (int blk = 0; blk < 2; ++blk) {
#pragma unroll
            for (int gg = 0; gg < 4; ++gg) {
                const int sko = blk * 32 + gg * 8 + hh * 4;
                B4 b0, b1;
                b0.s = *(const short4_*)&sVt[cur][n31 * TP + sko];
                b1.s = *(const short4_*)&sVt[cur][(32 + n31) * TP + sko];
                O0 = __builtin_amdgcn_mfma_f32_32x32x8bf16_1k(pfr[blk][gg].s, b0.s, O0, 0, 0, 0);
                O1 = __builtin_amdgcn_mfma_f32_32x32x8bf16_1k(pfr[blk][gg].s, b1.s, O1, 0, 0, 0);
                L_ = __builtin_amdgcn_mfma_f32_32x32x8bf16_1k(pfr[blk][gg].s, ones.s, L_, 0, 0, 0);
            }
        }
        __builtin_amdgcn_s_setprio(0);
#else
        __builtin_amdgcn_s_setprio(1);
#pragma unroll
        for (int blk = 0; blk < 2; ++blk) {
            B4 par[4];
#pragma unroll
            for (int gg = 0; gg < 4; ++gg) {
                par[gg].i[0] = __shfl_xor(pfr[blk][gg].i[0], 32);
                par[gg].i[1] = __shfl_xor(pfr[blk][gg].i[1], 32);
            }
#pragma unroll
            for (int w = 0; w < 2; ++w) {
                const int gsel = 2 * w + hh;
                B4 lo = (hh == 0) ? pfr[blk][gsel] : par[gsel];
                B4 hi = (hh == 0) ? par[gsel] : pfr[blk][gsel];
                B8 afr;
#pragma unroll
                for (int j = 0; j < 4; ++j) {
                    afr.u[j] = lo.u[j];
                    afr.u[4 + j] = hi.u[j];
                }
                const int sko = blk * 32 + w * 16 + hh * 8;
                B8 b0, b1;
                b0.s = *(const short8*)&sVt[cur][n31 * TP + sko];
                b1.s = *(const short8*)&sVt[cur][(32 + n31) * TP + sko];
                O0 = __builtin_amdgcn_mfma_f32_32x32x16_bf16(afr.b, b0.b, O0, 0, 0, 0);
                O1 = __builtin_amdgcn_mfma_f32_32x32x16_bf16(afr.b, b1.b, O1, 0, 0, 0);
                L_ = __builtin_amdgcn_mfma_f32_32x32x16_bf16(afr.b, ones8.b, L_, 0, 0, 0);
            }
        }
        __builtin_amdgcn_s_setprio(0);
#endif
        // --- write next tile into the other buffer (vmcnt waited here) ---
        if (kt < 15) {
            const int nb = 1 - cur;
            *(short8*)&sK[nb][srow * TP + sseg * 8] = nka;
            *(short8*)&sK[nb][(32 + srow) * TP + sseg * 8] = nkb;
            *(short8*)&sVt[nb][srow * TP + sseg * 8] = nva;
            *(short8*)&sVt[nb][(32 + srow) * TP + sseg * 8] = nvb;
        }
    }

    // --- epilogue: rows q=(r&3)+8*(r>>2)+4*hh; l from ones-MFMA (per-lane) ---
    unsigned short* obase = o + ((size_t)q0w * 4 + b) * 1024 + h * 64 + n31;
#pragma unroll
    for (int r = 0; r < 16; ++r) {
        const int qr = (r & 3) + 8 * (r >> 2) + 4 * hh;
        const float inv = RCP(L_[r]);
        obase[(size_t)qr * 4096] = f2bf_rne(O0[r] * inv);
        obase[(size_t)qr * 4096 + 32] = f2bf_rne(O1[r] * inv);
    }
}

extern "C" void kernel_launch(void* const* d_in, const int* in_sizes, int n_in,
                              void* d_out, int out_size, void* d_ws, size_t ws_size,
                              hipStream_t stream) {
    const float* query = (const float*)d_in[0];
    const float* key_ = (const float*)d_in[1];
    const float* value = (const float*)d_in[2];
    const int* key_mask = (const int*)d_in[3];
    const float* Wq = (const float*)d_in[4];
    const float* bq = (const float*)d_in[5];
    const float* Wk = (const float*)d_in[6];
    const float* bk = (const float*)d_in[7];
    const float* Wv = (const float*)d_in[8];
    const float* bv = (const float*)d_in[9];
    const float* Wo = (const float*)d_in[10];
    const float* bo = (const float*)d_in[11];
    float* out = (float*)d_out;

    const size_t NE = (size_t)4096 * 1024;
    unsigned short* q_ws = (unsigned short*)d_ws;
    unsigned short* k_ws = q_ws + NE;
    unsigned short* v_ws = k_ws + NE;   // holds V^T [(b,h,dh)][s]
    unsigned short* a_ws = v_ws + NE;   // attn output; doubles as qA before attn
    unsigned short* wt_ws = a_ws + NE;  // 4 x 1M bf16 weights

    // activation bf16 scratch: qA in a_ws (dead until attn writes it);
    // kA/vA in d_out (dead until out_gemm writes it; 16MB = 2 x 8MB).
    unsigned short* qA = a_ws;
    unsigned short* kA = (unsigned short*)d_out;
    unsigned short* vA = kA + NE;

    prep<<<dim3(16, 16, 16), 256, 0, stream>>>(Wq, Wk, Wv, Wo, query, key_, value,
                                               wt_ws, qA, kA, vA);
    qkv_gemm<<<dim3(32, 8, 3), 256, 0, stream>>>(qA, kA, vA, wt_ws,
                                                 bq, bk, bv, q_ws, k_ws, v_ws);
    attn_kernel<<<dim3(8, 4, 16), 256, 0, stream>>>(q_ws, k_ws, v_ws, key_mask, a_ws);
    out_gemm<<<dim3(32, 8, 1), 256, 0, stream>>>(a_ws, wt_ws, bo, out);
}

// Round 4
// 213.912 us; speedup vs baseline: 1.1787x; 1.0126x over previous
//
#include <hip/hip_runtime.h>
#include <hip/hip_bf16.h>

// MultiHeadAttention S=1024 B=4 D=1024 H=16 DH=64
// [0] prep: Wq/Wk/Wv/Wo f32 -> bf16 B^T[n][k]  (z=0..3)
//          query/key/value f32 -> bf16 row-major (z=4..15)
// [1] qkv_gemm: 128x128 GEMM, BK=32, DOUBLE-BUFFERED LDS (R4): one barrier per
//     K-step, stage(t+1) issued right after the barrier -> DMA latency hidden
//     under tile-t compute (catalog T3 "minimum 2-phase"). Total LDS still 32KB.
//     Both-sides XOR swizzle for BK=32: f(row)=(row>>1)&3 (write side folds to
//     global seg (l&3)^((l>>3)&3); read seg' = quad^((l15>>1)&3)) -> bank-balanced.
//     p=0,1: Q/K row-major out. p=2: operand-swapped -> V^T directly.
// [2] attn: flash-style, dbuf LDS, V pre-transposed, sBias table, XCD swizzle.
// [3] out_gemm (same template; 1 blk/CU so intra-block overlap matters most).
// ws (bf16 elems): q @0, k @NE, vT @2NE, attn_out/qA @3NE, WT(4x1M) @4NE (40MB)

typedef __attribute__((ext_vector_type(8))) short short8;
typedef __attribute__((ext_vector_type(4))) short short4_;
typedef __attribute__((ext_vector_type(4))) float f32x4;
typedef __attribute__((ext_vector_type(16))) float f32x16;
typedef __attribute__((ext_vector_type(8))) __bf16 bf16x8;
typedef __attribute__((ext_vector_type(4))) __bf16 bf16x4;

union B8 {
    short8 s;
    bf16x8 b;
    unsigned short u[8];
};
union B4 {
    short4_ s;
    bf16x4 b;
    unsigned short u[4];
    int i[2];
};

#if __has_builtin(__builtin_amdgcn_exp2f)
#define EXP2(x) __builtin_amdgcn_exp2f(x)
#else
#define EXP2(x) exp2f(x)
#endif
#if __has_builtin(__builtin_amdgcn_rcpf)
#define RCP(x) __builtin_amdgcn_rcpf(x)
#else
#define RCP(x) (1.0f / (x))
#endif

static __device__ __forceinline__ unsigned short f2bf_rne(float f) {
    union { float f; unsigned u; } v; v.f = f;
    unsigned r = v.u + 0x7FFFu + ((v.u >> 16) & 1u);
    return (unsigned short)(r >> 16);
}

static __device__ __forceinline__ void async_lds16(const void* g, const void* l) {
    __builtin_amdgcn_global_load_lds(
        (const __attribute__((address_space(1))) unsigned int*)(unsigned long long)g,
        (__attribute__((address_space(3))) unsigned int*)(unsigned int)(unsigned long long)l,
        16, 0, 0);
}

// ---------------------------------------------------------------------------
// Prep: z<4 weight transpose+convert; z>=4 activation f32->bf16 convert.
// ---------------------------------------------------------------------------
__global__ __launch_bounds__(256) void prep(
    const float* __restrict__ Wq, const float* __restrict__ Wk,
    const float* __restrict__ Wv, const float* __restrict__ Wo,
    const float* __restrict__ query, const float* __restrict__ key,
    const float* __restrict__ value,
    unsigned short* __restrict__ WT,
    unsigned short* __restrict__ qA, unsigned short* __restrict__ kA,
    unsigned short* __restrict__ vA) {
    const int t = threadIdx.x;
    const int z = blockIdx.z;

    if (z >= 4) {
        // activation convert: 12 slices x 1M elems; 256 blocks x 4096 elems.
        const int zz = z - 4;
        const int tensor = zz >> 2;
        const int part = zz & 3;
        const float* src = (tensor == 0) ? query : (tensor == 1) ? key : value;
        unsigned short* dst = (tensor == 0) ? qA : (tensor == 1) ? kA : vA;
        const int blk = blockIdx.y * 16 + blockIdx.x;
        const size_t base = (size_t)part * 1048576 + (size_t)blk * 4096 + t * 16;
        B8 w0, w1;
#pragma unroll
        for (int i = 0; i < 2; ++i) {
            f32x4 a = *(const f32x4*)(src + base + i * 8);
            f32x4 b = *(const f32x4*)(src + base + i * 8 + 4);
#pragma unroll
            for (int j = 0; j < 4; ++j) {
                (i ? w1 : w0).u[j] = f2bf_rne(a[j]);
                (i ? w1 : w0).u[4 + j] = f2bf_rne(b[j]);
            }
        }
        *(short8*)(dst + base) = w0.s;
        *(short8*)(dst + base + 8) = w1.s;
        return;
    }

    __shared__ float sT[64][65];
    const int dtile = blockIdx.x;
    const int sub = blockIdx.y;
    const float* src;
    int spitch;
    unsigned short* dst;
    if (z < 3) {
        const float* W = (z == 0) ? Wq : (z == 1) ? Wk : Wv;
        src = W + (size_t)sub * 65536 + (size_t)dtile * 64 * 64;
        spitch = 64;
        dst = WT + (size_t)z * 1048576 + (size_t)(sub * 64) * 1024 + dtile * 64;
    } else {
        src = Wo + (size_t)dtile * 64 * 1024 + sub * 64;
        spitch = 1024;
        dst = WT + (size_t)3 * 1048576 + (size_t)(sub * 64) * 1024 + dtile * 64;
    }

    const int r = t >> 2;
    const int cseg = (t & 3) * 16;
#pragma unroll
    for (int i = 0; i < 4; ++i) {
        f32x4 v = *(const f32x4*)(src + (size_t)r * spitch + cseg + i * 4);
#pragma unroll
        for (int j = 0; j < 4; ++j) sT[r][cseg + i * 4 + j] = v[j];
    }
    __syncthreads();
    B8 w0, w1;
#pragma unroll
    for (int i = 0; i < 8; ++i) {
        w0.u[i] = f2bf_rne(sT[cseg + i][r]);
        w1.u[i] = f2bf_rne(sT[cseg + 8 + i][r]);
    }
    *(short8*)(dst + (size_t)r * 1024 + cseg) = w0.s;
    *(short8*)(dst + (size_t)r * 1024 + cseg + 8) = w1.s;
}

// ---------------------------------------------------------------------------
// 128x128-tile GEMM, BK=32, double-buffered LDS (2x8KB per operand = 32KB).
// Pipeline per K-step: sync (DMA of tile t already landed during t-1 compute)
// -> issue stage(t+1 -> other buf) -> ds_read + 16 MFMA on buf[t&1].
// Swizzle: LDS[row][c] holds G[row][c ^ ((row>>1)&3)] (c = 16B segment).
//   write (DMA, 16 rows/inst, lane l -> row l>>2, seg l&3): global seg =
//     (l&3)^((l>>3)&3)   [since ((R+(l>>2))>>1)&3 = (l>>3)&3 for R%16==0]
//   read: seg' = quad ^ ((l15>>1)&3) -> 8 lanes per 16B granule x 8 granules
//     = perfectly balanced (the 8-cycle floor of a wave b128 read).
// ---------------------------------------------------------------------------
template <bool OUT_F32, bool BIAS_ROW>
__device__ __forceinline__ void gemm128(unsigned short* __restrict__ sA,
                                        unsigned short* __restrict__ sB,
                                        const unsigned short* __restrict__ A,
                                        size_t lda,
                                        const unsigned short* __restrict__ Bt,
                                        size_t ldb,
                                        const float* __restrict__ bias,
                                        void* __restrict__ Cv, size_t ldc,
                                        float oscale, int row0, int col0) {
    const int t = threadIdx.x;
    const int w = t >> 6;
    const int lane = t & 63;
    const int quad = lane >> 4;
    const int l15 = lane & 15;
    const int wr = w >> 1;
    const int wc = w & 1;
    const int srow16 = lane >> 2;                      // staging row within 16-row chunk
    const int sgseg = (lane & 3) ^ ((lane >> 3) & 3);  // pre-swizzled global 16B seg
    const int rseg = (quad ^ ((l15 >> 1) & 3)) * 8;    // read-side swizzled col (elems)

    f32x4 acc[4][4] = {};

    // per-wave staging base pointers (rows w*32 .. w*32+31, two 16-row chunks)
    const unsigned short* agp = A + (size_t)(row0 + w * 32 + srow16) * lda + sgseg * 8;
    const unsigned short* agp2 = agp + (size_t)16 * lda;
    const unsigned short* bgp = Bt + (size_t)(col0 + w * 32 + srow16) * ldb + sgseg * 8;
    const unsigned short* bgp2 = bgp + (size_t)16 * ldb;
    const int ldsA0 = (w * 32) * 32;  // elem offset of this wave's chunk
    const int ldsA1 = (w * 32 + 16) * 32;

    // prologue: stage K-step 0 into buffer 0
    async_lds16(agp, sA + ldsA0);
    async_lds16(agp2, sA + ldsA1);
    async_lds16(bgp, sB + ldsA0);
    async_lds16(bgp2, sB + ldsA1);

#pragma unroll 2
    for (int tt = 0; tt < 32; ++tt) {
        const int cur = tt & 1;
        __syncthreads();  // implicit vmcnt(0)+lgkmcnt(0): tile tt ready, other buf free
        if (tt < 31) {
            const int nb = cur ^ 1;
            const int k0 = (tt + 1) * 32;  // elems
            async_lds16(agp + k0, sA + nb * 4096 + ldsA0);
            async_lds16(agp2 + k0, sA + nb * 4096 + ldsA1);
            async_lds16(bgp + k0, sB + nb * 4096 + ldsA0);
            async_lds16(bgp2 + k0, sB + nb * 4096 + ldsA1);
        }
        const unsigned short* sac = sA + cur * 4096;
        const unsigned short* sbc = sB + cur * 4096;
        B8 af[4], bf[4];
#pragma unroll
        for (int i = 0; i < 4; ++i)
            af[i].s = *(const short8*)&sac[(wr * 64 + i * 16 + l15) * 32 + rseg];
#pragma unroll
        for (int j = 0; j < 4; ++j)
            bf[j].s = *(const short8*)&sbc[(wc * 64 + j * 16 + l15) * 32 + rseg];
#pragma unroll
        for (int i = 0; i < 4; ++i)
#pragma unroll
            for (int j = 0; j < 4; ++j)
                acc[i][j] = __builtin_amdgcn_mfma_f32_16x16x32_bf16(af[i].b, bf[j].b,
                                                                    acc[i][j], 0, 0, 0);
    }

    float brow[4][4];
    if constexpr (BIAS_ROW) {
#pragma unroll
        for (int i = 0; i < 4; ++i)
#pragma unroll
            for (int r = 0; r < 4; ++r)
                brow[i][r] = bias[row0 + wr * 64 + i * 16 + quad * 4 + r];
    }
#pragma unroll
    for (int j = 0; j < 4; ++j) {
        const int col = col0 + wc * 64 + j * 16 + l15;
        const float bcol = BIAS_ROW ? 0.0f : bias[col];
#pragma unroll
        for (int i = 0; i < 4; ++i) {
#pragma unroll
            for (int r = 0; r < 4; ++r) {
                const int row = row0 + wr * 64 + i * 16 + quad * 4 + r;
                const size_t idx = (size_t)row * ldc + col;
                const float bb = BIAS_ROW ? brow[i][r] : bcol;
                const float val = (acc[i][j][r] + bb) * oscale;
                if constexpr (OUT_F32)
                    ((float*)Cv)[idx] = val;
                else
                    ((unsigned short*)Cv)[idx] = f2bf_rne(val);
            }
        }
    }
}

#define SCALE_L2E 0.18033688011112042f  // (1/8) * log2(e)

__global__ __launch_bounds__(256) void qkv_gemm(
    const unsigned short* __restrict__ qA, const unsigned short* __restrict__ kA,
    const unsigned short* __restrict__ vA,
    const unsigned short* __restrict__ WT,
    const float* __restrict__ bq, const float* __restrict__ bk, const float* __restrict__ bv,
    unsigned short* q_o, unsigned short* k_o, unsigned short* vT_o) {
    __shared__ unsigned short sA[2 * 128 * 32];
    __shared__ unsigned short sB[2 * 128 * 32];
    const int p = blockIdx.z;
    if (p < 2) {
        const unsigned short* A = (p == 0) ? qA : kA;
        const unsigned short* Bt = WT + (size_t)p * 1048576;
        const float* bias = (p == 0) ? bq : bk;
        unsigned short* C = (p == 0) ? q_o : k_o;
        const float osc = (p == 0) ? SCALE_L2E : 1.0f;  // pre-scale q for attn exp2
        gemm128<false, false>(sA, sB, A, 1024, Bt, 1024, bias, C, 1024, osc,
                              blockIdx.x * 128, blockIdx.y * 128);
    } else {
        // V^T: per batch b, C[colV][s] = sum_d Wv^T[colV][d] * vA[(s*4+b)][d]
        // A = Wv^T (WT slot 2), Bt = vA rows strided 4 (ldb=4096), bias per-row.
        const int b = blockIdx.x >> 3;
        const int rt = blockIdx.x & 7;
        gemm128<false, true>(sA, sB, WT + (size_t)2 * 1048576, 1024,
                             vA + (size_t)b * 1024, 4096, bv,
                             vT_o + (size_t)b * 1048576, 1024, 1.0f,
                             rt * 128, blockIdx.y * 128);
    }
}

__global__ __launch_bounds__(256) void out_gemm(const unsigned short* __restrict__ A,
                                                const unsigned short* __restrict__ WT,
                                                const float* __restrict__ bo,
                                                float* __restrict__ C) {
    __shared__ unsigned short sA[2 * 128 * 32];
    __shared__ unsigned short sB[2 * 128 * 32];
    gemm128<true, false>(sA, sB, A, 1024, WT + (size_t)3 * 1048576, 1024, bo, C, 1024,
                         1.0f, blockIdx.x * 128, blockIdx.y * 128);
}

// ---------------------------------------------------------------------------
// Flash-style attention, double-buffered LDS, 1 sync per k-tile.
// V comes in pre-transposed (vT[(b,h,dh)][s]) -> staged exactly like K.
// Mask bias via sBias LDS table. XCD-pinning swizzle + setprio.
// ---------------------------------------------------------------------------
#define TP 72

#if __has_builtin(__builtin_amdgcn_mfma_f32_32x32x8bf16_1k)
#define HAVE_X8 1
#endif

__global__ __launch_bounds__(256) void attn_kernel(
    const unsigned short* __restrict__ q,   // pre-scaled by log2(e)/8
    const unsigned short* __restrict__ k,
    const unsigned short* __restrict__ vT,  // [(b*16+h)*64+dh][s]
    const int* __restrict__ key_mask,
    unsigned short* __restrict__ o) {
    __shared__ unsigned short sK[2][64 * TP];
    __shared__ unsigned short sVt[2][64 * TP];
    __shared__ float sBias[1024];  // [kt][blk][hh][r]
    __shared__ unsigned long long sBits[16];

    const int t = threadIdx.x;
    const int wave = t >> 6;
    const int lane = t & 63;
    const int n31 = lane & 31;
    const int hh = lane >> 5;

    // XCD-pinning swizzle: all 8 q-tiles of a (b,h) group get the same
    // (linear_id % 8) => same XCD => K/V (512KB) fetched once into that L2.
    const int L = blockIdx.x + 8 * (blockIdx.y + 4 * blockIdx.z);  // 0..511
    const int xcd = L & 7;
    const int kk = L >> 3;                  // 0..63
    const int g = (xcd << 3) | (kk >> 3);   // (b,h) group 0..63
    const int qt = kk & 7;                  // q-tile 0..7
    const int b = g & 3;
    const int h = g >> 2;
    const int q0w = qt * 128 + wave * 32;

    const int srow = t >> 3;  // 0..31
    const int sseg = t & 7;   // 0..7

    // mask bits: bit set => masked out
#pragma unroll
    for (int i = 0; i < 4; ++i) {
        const int idx = i * 4 + wave;
        const int sk = idx * 64 + lane;
        unsigned long long bal = __ballot(key_mask[sk * 4 + b] != 0);
        if (lane == 0) sBits[idx] = bal;
    }
    __syncthreads();
    // accumulator-init bias table: -16384 => exp2 underflow => exact 0
#pragma unroll
    for (int i = 0; i < 4; ++i) {
        const int idx = t * 4 + i;  // 0..1023 = [kt][blk][hh][r]
        const int r = idx & 15;
        const int hb = (idx >> 4) & 1;
        const int blk = (idx >> 5) & 1;
        const int kt = idx >> 6;
        const int row = (r & 3) + 8 * (r >> 2) + 4 * hb + blk * 32;
        sBias[idx] = ((sBits[kt] >> row) & 1ull) ? -16384.0f : 0.0f;
    }

    // Q fragments (B-operand of 32x32x16): B[n=lane&31][k=hh*8+j]
    bf16x8 qf[4];
    {
        const unsigned short* qrow =
            q + ((size_t)(q0w + n31) * 4 + b) * 1024 + h * 64 + hh * 8;
#pragma unroll
        for (int kc = 0; kc < 4; ++kc) {
            B8 tmp;
            tmp.s = *(const short8*)(qrow + kc * 16);
            qf[kc] = tmp.b;
        }
    }

    f32x16 O0 = {}, O1 = {}, L_ = {};
    B4 ones;
#pragma unroll
    for (int j = 0; j < 4; ++j) ones.u[j] = 0x3F80;  // bf16 1.0
#if !defined(HAVE_X8)
    B8 ones8;
#pragma unroll
    for (int j = 0; j < 8; ++j) ones8.u[j] = 0x3F80;
#endif

    const unsigned short* kbase = k + (size_t)b * 1024 + h * 64;
    const unsigned short* vtb = vT + ((size_t)(b * 16 + h) * 64) * 1024;

    // prologue: stage tile 0 into buffer 0 (V staged like K: rows = dh)
    {
        const unsigned short* kr = kbase + (size_t)srow * 4096 + sseg * 8;
        short8 ka = *(const short8*)kr;
        short8 kb2 = *(const short8*)(kr + (size_t)32 * 4096);
        const unsigned short* vr = vtb + (size_t)srow * 1024 + sseg * 8;
        short8 va = *(const short8*)vr;
        short8 vb2 = *(const short8*)(vr + (size_t)32 * 1024);
        *(short8*)&sK[0][srow * TP + sseg * 8] = ka;
        *(short8*)&sK[0][(32 + srow) * TP + sseg * 8] = kb2;
        *(short8*)&sVt[0][srow * TP + sseg * 8] = va;
        *(short8*)&sVt[0][(32 + srow) * TP + sseg * 8] = vb2;
    }

#pragma unroll 2
    for (int kt = 0; kt < 16; ++kt) {
        const int cur = kt & 1;
        __syncthreads();
        // issue next tile's global loads (completion awaited at ds_write below)
        short8 nka, nkb, nva, nvb;
        if (kt < 15) {
            const int k0n = (kt + 1) * 64;
            const unsigned short* kr = kbase + (size_t)(k0n + srow) * 4096 + sseg * 8;
            nka = *(const short8*)kr;
            nkb = *(const short8*)(kr + (size_t)32 * 4096);
            const unsigned short* vr = vtb + (size_t)srow * 1024 + k0n + sseg * 8;
            nva = *(const short8*)vr;
            nvb = *(const short8*)(vr + (size_t)32 * 1024);
        }
        // --- S^T = K·Q^T with mask-bias accumulator init; exp2; pack bf16 ---
        B4 pfr[2][4];
#pragma unroll
        for (int blk = 0; blk < 2; ++blk) {
            f32x16 c;
            const f32x4* bp = (const f32x4*)&sBias[((kt * 2 + blk) * 2 + hh) * 16];
#pragma unroll
            for (int i = 0; i < 4; ++i) {
                f32x4 x = bp[i];
#pragma unroll
                for (int j = 0; j < 4; ++j) c[i * 4 + j] = x[j];
            }
            __builtin_amdgcn_s_setprio(1);
#pragma unroll
            for (int kc = 0; kc < 4; ++kc) {
                B8 af;
                af.s = *(const short8*)&sK[cur][(blk * 32 + n31) * TP + kc * 16 + hh * 8];
                c = __builtin_amdgcn_mfma_f32_32x32x16_bf16(af.b, qf[kc], c, 0, 0, 0);
            }
            __builtin_amdgcn_s_setprio(0);
#pragma unroll
            for (int gg = 0; gg < 4; ++gg)
#pragma unroll
                for (int j = 0; j < 4; ++j)
                    pfr[blk][gg].b[j] = (__bf16)EXP2(c[gg * 4 + j]);
        }
        // --- O += P·V, l += P·1 ---
#if defined(HAVE_X8)
        __builtin_amdgcn_s_setprio(1);
#pragma unroll
        for (int blk = 0; blk < 2; ++blk) {
#pragma unroll
            for (int gg = 0; gg < 4; ++gg) {
                const int sko = blk * 32 + gg * 8 + hh * 4;
                B4 b0, b1;
                b0.s = *(const short4_*)&sVt[cur][n31 * TP + sko];
                b1.s = *(const short4_*)&sVt[cur][(32 + n31) * TP + sko];
                O0 = __builtin_amdgcn_mfma_f32_32x32x8bf16_1k(pfr[blk][gg].s, b0.s, O0, 0, 0, 0);
                O1 = __builtin_amdgcn_mfma_f32_32x32x8bf16_1k(pfr[blk][gg].s, b1.s, O1, 0, 0, 0);
                L_ = __builtin_amdgcn_mfma_f32_32x32x8bf16_1k(pfr[blk][gg].s, ones.s, L_, 0, 0, 0);
            }
        }
        __builtin_amdgcn_s_setprio(0);
#else
        __builtin_amdgcn_s_setprio(1);
#pragma unroll
        for (int blk = 0; blk < 2; ++blk) {
            B4 par[4];
#pragma unroll
            for (int gg = 0; gg < 4; ++gg) {
                par[gg].i[0] = __shfl_xor(pfr[blk][gg].i[0], 32);
                par[gg].i[1] = __shfl_xor(pfr[blk][gg].i[1], 32);
            }
#pragma unroll
            for (int w = 0; w < 2; ++w) {
                const int gsel = 2 * w + hh;
                B4 lo = (hh == 0) ? pfr[blk][gsel] : par[gsel];
                B4 hi = (hh == 0) ? par[gsel] : pfr[blk][gsel];
                B8 afr;
#pragma unroll
                for (int j = 0; j < 4; ++j) {
                    afr.u[j] = lo.u[j];
                    afr.u[4 + j] = hi.u[j];
                }
                const int sko = blk * 32 + w * 16 + hh * 8;
                B8 b0, b1;
                b0.s = *(const short8*)&sVt[cur][n31 * TP + sko];
                b1.s = *(const short8*)&sVt[cur][(32 + n31) * TP + sko];
                O0 = __builtin_amdgcn_mfma_f32_32x32x16_bf16(afr.b, b0.b, O0, 0, 0, 0);
                O1 = __builtin_amdgcn_mfma_f32_32x32x16_bf16(afr.b, b1.b, O1, 0, 0, 0);
                L_ = __builtin_amdgcn_mfma_f32_32x32x16_bf16(afr.b, ones8.b, L_, 0, 0, 0);
            }
        }
        __builtin_amdgcn_s_setprio(0);
#endif
        // --- write next tile into the other buffer (vmcnt waited here) ---
        if (kt < 15) {
            const int nb = 1 - cur;
            *(short8*)&sK[nb][srow * TP + sseg * 8] = nka;
            *(short8*)&sK[nb][(32 + srow) * TP + sseg * 8] = nkb;
            *(short8*)&sVt[nb][srow * TP + sseg * 8] = nva;
            *(short8*)&sVt[nb][(32 + srow) * TP + sseg * 8] = nvb;
        }
    }

    // --- epilogue: rows q=(r&3)+8*(r>>2)+4*hh; l from ones-MFMA (per-lane) ---
    unsigned short* obase = o + ((size_t)q0w * 4 + b) * 1024 + h * 64 + n31;
#pragma unroll
    for (int r = 0; r < 16; ++r) {
        const int qr = (r & 3) + 8 * (r >> 2) + 4 * hh;
        const float inv = RCP(L_[r]);
        obase[(size_t)qr * 4096] = f2bf_rne(O0[r] * inv);
        obase[(size_t)qr * 4096 + 32] = f2bf_rne(O1[r] * inv);
    }
}

extern "C" void kernel_launch(void* const* d_in, const int* in_sizes, int n_in,
                              void* d_out, int out_size, void* d_ws, size_t ws_size,
                              hipStream_t stream) {
    const float* query = (const float*)d_in[0];
    const float* key_ = (const float*)d_in[1];
    const float* value = (const float*)d_in[2];
    const int* key_mask = (const int*)d_in[3];
    const float* Wq = (const float*)d_in[4];
    const float* bq = (const float*)d_in[5];
    const float* Wk = (const float*)d_in[6];
    const float* bk = (const float*)d_in[7];
    const float* Wv = (const float*)d_in[8];
    const float* bv = (const float*)d_in[9];
    const float* Wo = (const float*)d_in[10];
    const float* bo = (const float*)d_in[11];
    float* out = (float*)d_out;

    const size_t NE = (size_t)4096 * 1024;
    unsigned short* q_ws = (unsigned short*)d_ws;
    unsigned short* k_ws = q_ws + NE;
    unsigned short* v_ws = k_ws + NE;   // holds V^T [(b,h,dh)][s]
    unsigned short* a_ws = v_ws + NE;   // attn output; doubles as qA before attn
    unsigned short* wt_ws = a_ws + NE;  // 4 x 1M bf16 weights

    // activation bf16 scratch: qA in a_ws (dead until attn writes it);
    // kA/vA in d_out (dead until out_gemm writes it; 16MB = 2 x 8MB).
    unsigned short* qA = a_ws;
    unsigned short* kA = (unsigned short*)d_out;
    unsigned short* vA = kA + NE;

    prep<<<dim3(16, 16, 16), 256, 0, stream>>>(Wq, Wk, Wv, Wo, query, key_, value,
                                               wt_ws, qA, kA, vA);
    qkv_gemm<<<dim3(32, 8, 3), 256, 0, stream>>>(qA, kA, vA, wt_ws,
                                                 bq, bk, bv, q_ws, k_ws, v_ws);
    attn_kernel<<<dim3(8, 4, 16), 256, 0, stream>>>(q_ws, k_ws, v_ws, key_mask, a_ws);
    out_gemm<<<dim3(32, 8, 1), 256, 0, stream>>>(a_ws, wt_ws, bo, out);
}

// Round 5
// 199.906 us; speedup vs baseline: 1.2613x; 1.0701x over previous
//
#include <hip/hip_runtime.h>
#include <hip/hip_bf16.h>

// MultiHeadAttention S=1024 B=4 D=1024 H=16 DH=64
// [0] prep: Wq/Wk/Wv/Wo f32 -> bf16 B^T[n][k]  (z=0..3)
//          query/key/value f32 -> bf16 row-major (z=4..15)
// [1] qkv_gemm: 128x128 GEMM, BK=32. R5: 3-buffer 2-deep pipeline with COUNTED
//     vmcnt(4) + raw s_barrier (T3+T4): loads(t+2) issued at step t, waited at
//     t+2 -> 2 compute phases in flight; never vmcnt(0) in the loop.
//     LDS 48KB = 3 blocks/CU = exactly the grid's demand. Both-sides XOR swizzle
//     (BK=32): write seg (l&3)^((l>>3)&3), read seg quad^((l15>>1)&3).
//     p=0,1: Q/K row-major out. p=2: operand-swapped -> V^T directly.
// [2] attn: flash-style, dbuf LDS, V pre-transposed, sBias table, XCD swizzle.
// [3] out_gemm (same template).
// ws (bf16 elems): q @0, k @NE, vT @2NE, attn_out/qA @3NE, WT(4x1M) @4NE (40MB)

typedef __attribute__((ext_vector_type(8))) short short8;
typedef __attribute__((ext_vector_type(4))) short short4_;
typedef __attribute__((ext_vector_type(4))) float f32x4;
typedef __attribute__((ext_vector_type(16))) float f32x16;
typedef __attribute__((ext_vector_type(8))) __bf16 bf16x8;
typedef __attribute__((ext_vector_type(4))) __bf16 bf16x4;

union B8 {
    short8 s;
    bf16x8 b;
    unsigned short u[8];
};
union B4 {
    short4_ s;
    bf16x4 b;
    unsigned short u[4];
    int i[2];
};

#if __has_builtin(__builtin_amdgcn_exp2f)
#define EXP2(x) __builtin_amdgcn_exp2f(x)
#else
#define EXP2(x) exp2f(x)
#endif
#if __has_builtin(__builtin_amdgcn_rcpf)
#define RCP(x) __builtin_amdgcn_rcpf(x)
#else
#define RCP(x) (1.0f / (x))
#endif

static __device__ __forceinline__ unsigned short f2bf_rne(float f) {
    union { float f; unsigned u; } v; v.f = f;
    unsigned r = v.u + 0x7FFFu + ((v.u >> 16) & 1u);
    return (unsigned short)(r >> 16);
}

static __device__ __forceinline__ void async_lds16(const void* g, const void* l) {
    __builtin_amdgcn_global_load_lds(
        (const __attribute__((address_space(1))) unsigned int*)(unsigned long long)g,
        (__attribute__((address_space(3))) unsigned int*)(unsigned int)(unsigned long long)l,
        16, 0, 0);
}

// ---------------------------------------------------------------------------
// Prep: z<4 weight transpose+convert; z>=4 activation f32->bf16 convert.
// ---------------------------------------------------------------------------
__global__ __launch_bounds__(256) void prep(
    const float* __restrict__ Wq, const float* __restrict__ Wk,
    const float* __restrict__ Wv, const float* __restrict__ Wo,
    const float* __restrict__ query, const float* __restrict__ key,
    const float* __restrict__ value,
    unsigned short* __restrict__ WT,
    unsigned short* __restrict__ qA, unsigned short* __restrict__ kA,
    unsigned short* __restrict__ vA) {
    const int t = threadIdx.x;
    const int z = blockIdx.z;

    if (z >= 4) {
        // activation convert: 12 slices x 1M elems; 256 blocks x 4096 elems.
        const int zz = z - 4;
        const int tensor = zz >> 2;
        const int part = zz & 3;
        const float* src = (tensor == 0) ? query : (tensor == 1) ? key : value;
        unsigned short* dst = (tensor == 0) ? qA : (tensor == 1) ? kA : vA;
        const int blk = blockIdx.y * 16 + blockIdx.x;
        const size_t base = (size_t)part * 1048576 + (size_t)blk * 4096 + t * 16;
        B8 w0, w1;
#pragma unroll
        for (int i = 0; i < 2; ++i) {
            f32x4 a = *(const f32x4*)(src + base + i * 8);
            f32x4 b = *(const f32x4*)(src + base + i * 8 + 4);
#pragma unroll
            for (int j = 0; j < 4; ++j) {
                (i ? w1 : w0).u[j] = f2bf_rne(a[j]);
                (i ? w1 : w0).u[4 + j] = f2bf_rne(b[j]);
            }
        }
        *(short8*)(dst + base) = w0.s;
        *(short8*)(dst + base + 8) = w1.s;
        return;
    }

    __shared__ float sT[64][65];
    const int dtile = blockIdx.x;
    const int sub = blockIdx.y;
    const float* src;
    int spitch;
    unsigned short* dst;
    if (z < 3) {
        const float* W = (z == 0) ? Wq : (z == 1) ? Wk : Wv;
        src = W + (size_t)sub * 65536 + (size_t)dtile * 64 * 64;
        spitch = 64;
        dst = WT + (size_t)z * 1048576 + (size_t)(sub * 64) * 1024 + dtile * 64;
    } else {
        src = Wo + (size_t)dtile * 64 * 1024 + sub * 64;
        spitch = 1024;
        dst = WT + (size_t)3 * 1048576 + (size_t)(sub * 64) * 1024 + dtile * 64;
    }

    const int r = t >> 2;
    const int cseg = (t & 3) * 16;
#pragma unroll
    for (int i = 0; i < 4; ++i) {
        f32x4 v = *(const f32x4*)(src + (size_t)r * spitch + cseg + i * 4);
#pragma unroll
        for (int j = 0; j < 4; ++j) sT[r][cseg + i * 4 + j] = v[j];
    }
    __syncthreads();
    B8 w0, w1;
#pragma unroll
    for (int i = 0; i < 8; ++i) {
        w0.u[i] = f2bf_rne(sT[cseg + i][r]);
        w1.u[i] = f2bf_rne(sT[cseg + 8 + i][r]);
    }
    *(short8*)(dst + (size_t)r * 1024 + cseg) = w0.s;
    *(short8*)(dst + (size_t)r * 1024 + cseg + 8) = w1.s;
}

// ---------------------------------------------------------------------------
// 128x128-tile GEMM, BK=32, 3-buffer 2-deep counted-vmcnt pipeline.
// Per step t: s_waitcnt vmcnt(4) [loads(t) landed; loads(t+1) in flight]
//   -> raw s_barrier [all waves' loads(t) visible; all reads of buf((t+2)%3)
//      finished in step t-1] -> issue loads(t+2) -> ds_read(t) + 16 MFMA.
// vmcnt accounting: the K-loop contains NO other VMEM ops (4 DMA insts/tile).
// Swizzle: LDS[row][c] holds G[row][c ^ ((row>>1)&3)] (c = 16B segment).
// ---------------------------------------------------------------------------
template <bool OUT_F32, bool BIAS_ROW>
__device__ __forceinline__ void gemm128(unsigned short* __restrict__ sA,
                                        unsigned short* __restrict__ sB,
                                        const unsigned short* __restrict__ A,
                                        size_t lda,
                                        const unsigned short* __restrict__ Bt,
                                        size_t ldb,
                                        const float* __restrict__ bias,
                                        void* __restrict__ Cv, size_t ldc,
                                        float oscale, int row0, int col0) {
    const int t = threadIdx.x;
    const int w = t >> 6;
    const int lane = t & 63;
    const int quad = lane >> 4;
    const int l15 = lane & 15;
    const int wr = w >> 1;
    const int wc = w & 1;
    const int srow16 = lane >> 2;                      // staging row within 16-row chunk
    const int sgseg = (lane & 3) ^ ((lane >> 3) & 3);  // pre-swizzled global 16B seg
    const int rseg = (quad ^ ((l15 >> 1) & 3)) * 8;    // read-side swizzled col (elems)

    f32x4 acc[4][4] = {};

    // per-wave staging base pointers (rows w*32 .. w*32+31, two 16-row chunks)
    const unsigned short* agp = A + (size_t)(row0 + w * 32 + srow16) * lda + sgseg * 8;
    const unsigned short* agp2 = agp + (size_t)16 * lda;
    const unsigned short* bgp = Bt + (size_t)(col0 + w * 32 + srow16) * ldb + sgseg * 8;
    const unsigned short* bgp2 = bgp + (size_t)16 * ldb;
    const int ldsA0 = (w * 32) * 32;  // elem offset of this wave's chunk
    const int ldsA1 = (w * 32 + 16) * 32;

    auto STAGE = [&](int tt, int off) {
        const int k0 = tt * 32;
        async_lds16(agp + k0, sA + off + ldsA0);
        async_lds16(agp2 + k0, sA + off + ldsA1);
        async_lds16(bgp + k0, sB + off + ldsA0);
        async_lds16(bgp2 + k0, sB + off + ldsA1);
    };
    auto COMPUTE = [&](int off) {
        const unsigned short* sac = sA + off;
        const unsigned short* sbc = sB + off;
        B8 af[4], bf[4];
#pragma unroll
        for (int i = 0; i < 4; ++i)
            af[i].s = *(const short8*)&sac[(wr * 64 + i * 16 + l15) * 32 + rseg];
#pragma unroll
        for (int j = 0; j < 4; ++j)
            bf[j].s = *(const short8*)&sbc[(wc * 64 + j * 16 + l15) * 32 + rseg];
#pragma unroll
        for (int i = 0; i < 4; ++i)
#pragma unroll
            for (int j = 0; j < 4; ++j)
                acc[i][j] = __builtin_amdgcn_mfma_f32_16x16x32_bf16(af[i].b, bf[j].b,
                                                                    acc[i][j], 0, 0, 0);
    };

    // prologue: tiles 0,1 in flight (8 outstanding DMA insts)
    STAGE(0, 0);
    STAGE(1, 4096);

    // tiles 0..29: wait own loads(t) [vmcnt(4)], barrier, prefetch t+2, compute t
    for (int t3 = 0; t3 < 30; t3 += 3) {
        asm volatile("s_waitcnt vmcnt(4)" ::: "memory");
        __builtin_amdgcn_s_barrier();
        STAGE(t3 + 2, 8192);
        COMPUTE(0);
        asm volatile("s_waitcnt vmcnt(4)" ::: "memory");
        __builtin_amdgcn_s_barrier();
        STAGE(t3 + 3, 0);
        COMPUTE(4096);
        asm volatile("s_waitcnt vmcnt(4)" ::: "memory");
        __builtin_amdgcn_s_barrier();
        STAGE(t3 + 4, 4096);
        COMPUTE(8192);
    }
    // tile 30 (loads(31) still in flight)
    asm volatile("s_waitcnt vmcnt(4)" ::: "memory");
    __builtin_amdgcn_s_barrier();
    COMPUTE(0);
    // tile 31 (final drain)
    asm volatile("s_waitcnt vmcnt(0)" ::: "memory");
    __builtin_amdgcn_s_barrier();
    COMPUTE(4096);

    float brow[4][4];
    if constexpr (BIAS_ROW) {
#pragma unroll
        for (int i = 0; i < 4; ++i)
#pragma unroll
            for (int r = 0; r < 4; ++r)
                brow[i][r] = bias[row0 + wr * 64 + i * 16 + quad * 4 + r];
    }
#pragma unroll
    for (int j = 0; j < 4; ++j) {
        const int col = col0 + wc * 64 + j * 16 + l15;
        const float bcol = BIAS_ROW ? 0.0f : bias[col];
#pragma unroll
        for (int i = 0; i < 4; ++i) {
#pragma unroll
            for (int r = 0; r < 4; ++r) {
                const int row = row0 + wr * 64 + i * 16 + quad * 4 + r;
                const size_t idx = (size_t)row * ldc + col;
                const float bb = BIAS_ROW ? brow[i][r] : bcol;
                const float val = (acc[i][j][r] + bb) * oscale;
                if constexpr (OUT_F32)
                    ((float*)Cv)[idx] = val;
                else
                    ((unsigned short*)Cv)[idx] = f2bf_rne(val);
            }
        }
    }
}

#define SCALE_L2E 0.18033688011112042f  // (1/8) * log2(e)

__global__ __launch_bounds__(256) void qkv_gemm(
    const unsigned short* __restrict__ qA, const unsigned short* __restrict__ kA,
    const unsigned short* __restrict__ vA,
    const unsigned short* __restrict__ WT,
    const float* __restrict__ bq, const float* __restrict__ bk, const float* __restrict__ bv,
    unsigned short* q_o, unsigned short* k_o, unsigned short* vT_o) {
    __shared__ unsigned short sA[3 * 128 * 32];
    __shared__ unsigned short sB[3 * 128 * 32];
    const int p = blockIdx.z;
    if (p < 2) {
        const unsigned short* A = (p == 0) ? qA : kA;
        const unsigned short* Bt = WT + (size_t)p * 1048576;
        const float* bias = (p == 0) ? bq : bk;
        unsigned short* C = (p == 0) ? q_o : k_o;
        const float osc = (p == 0) ? SCALE_L2E : 1.0f;  // pre-scale q for attn exp2
        gemm128<false, false>(sA, sB, A, 1024, Bt, 1024, bias, C, 1024, osc,
                              blockIdx.x * 128, blockIdx.y * 128);
    } else {
        // V^T: per batch b, C[colV][s] = sum_d Wv^T[colV][d] * vA[(s*4+b)][d]
        // A = Wv^T (WT slot 2), Bt = vA rows strided 4 (ldb=4096), bias per-row.
        const int b = blockIdx.x >> 3;
        const int rt = blockIdx.x & 7;
        gemm128<false, true>(sA, sB, WT + (size_t)2 * 1048576, 1024,
                             vA + (size_t)b * 1024, 4096, bv,
                             vT_o + (size_t)b * 1048576, 1024, 1.0f,
                             rt * 128, blockIdx.y * 128);
    }
}

__global__ __launch_bounds__(256) void out_gemm(const unsigned short* __restrict__ A,
                                                const unsigned short* __restrict__ WT,
                                                const float* __restrict__ bo,
                                                float* __restrict__ C) {
    __shared__ unsigned short sA[3 * 128 * 32];
    __shared__ unsigned short sB[3 * 128 * 32];
    gemm128<true, false>(sA, sB, A, 1024, WT + (size_t)3 * 1048576, 1024, bo, C, 1024,
                         1.0f, blockIdx.x * 128, blockIdx.y * 128);
}

// ---------------------------------------------------------------------------
// Flash-style attention, double-buffered LDS, 1 sync per k-tile.
// V comes in pre-transposed (vT[(b,h,dh)][s]) -> staged exactly like K.
// Mask bias via sBias LDS table. XCD-pinning swizzle + setprio.
// ---------------------------------------------------------------------------
#define TP 72

#if __has_builtin(__builtin_amdgcn_mfma_f32_32x32x8bf16_1k)
#define HAVE_X8 1
#endif

__global__ __launch_bounds__(256) void attn_kernel(
    const unsigned short* __restrict__ q,   // pre-scaled by log2(e)/8
    const unsigned short* __restrict__ k,
    const unsigned short* __restrict__ vT,  // [(b*16+h)*64+dh][s]
    const int* __restrict__ key_mask,
    unsigned short* __restrict__ o) {
    __shared__ unsigned short sK[2][64 * TP];
    __shared__ unsigned short sVt[2][64 * TP];
    __shared__ float sBias[1024];  // [kt][blk][hh][r]
    __shared__ unsigned long long sBits[16];

    const int t = threadIdx.x;
    const int wave = t >> 6;
    const int lane = t & 63;
    const int n31 = lane & 31;
    const int hh = lane >> 5;

    // XCD-pinning swizzle: all 8 q-tiles of a (b,h) group get the same
    // (linear_id % 8) => same XCD => K/V (512KB) fetched once into that L2.
    const int L = blockIdx.x + 8 * (blockIdx.y + 4 * blockIdx.z);  // 0..511
    const int xcd = L & 7;
    const int kk = L >> 3;                  // 0..63
    const int g = (xcd << 3) | (kk >> 3);   // (b,h) group 0..63
    const int qt = kk & 7;                  // q-tile 0..7
    const int b = g & 3;
    const int h = g >> 2;
    const int q0w = qt * 128 + wave * 32;

    const int srow = t >> 3;  // 0..31
    const int sseg = t & 7;   // 0..7

    // mask bits: bit set => masked out
#pragma unroll
    for (int i = 0; i < 4; ++i) {
        const int idx = i * 4 + wave;
        const int sk = idx * 64 + lane;
        unsigned long long bal = __ballot(key_mask[sk * 4 + b] != 0);
        if (lane == 0) sBits[idx] = bal;
    }
    __syncthreads();
    // accumulator-init bias table: -16384 => exp2 underflow => exact 0
#pragma unroll
    for (int i = 0; i < 4; ++i) {
        const int idx = t * 4 + i;  // 0..1023 = [kt][blk][hh][r]
        const int r = idx & 15;
        const int hb = (idx >> 4) & 1;
        const int blk = (idx >> 5) & 1;
        const int kt = idx >> 6;
        const int row = (r & 3) + 8 * (r >> 2) + 4 * hb + blk * 32;
        sBias[idx] = ((sBits[kt] >> row) & 1ull) ? -16384.0f : 0.0f;
    }

    // Q fragments (B-operand of 32x32x16): B[n=lane&31][k=hh*8+j]
    bf16x8 qf[4];
    {
        const unsigned short* qrow =
            q + ((size_t)(q0w + n31) * 4 + b) * 1024 + h * 64 + hh * 8;
#pragma unroll
        for (int kc = 0; kc < 4; ++kc) {
            B8 tmp;
            tmp.s = *(const short8*)(qrow + kc * 16);
            qf[kc] = tmp.b;
        }
    }

    f32x16 O0 = {}, O1 = {}, L_ = {};
    B4 ones;
#pragma unroll
    for (int j = 0; j < 4; ++j) ones.u[j] = 0x3F80;  // bf16 1.0
#if !defined(HAVE_X8)
    B8 ones8;
#pragma unroll
    for (int j = 0; j < 8; ++j) ones8.u[j] = 0x3F80;
#endif

    const unsigned short* kbase = k + (size_t)b * 1024 + h * 64;
    const unsigned short* vtb = vT + ((size_t)(b * 16 + h) * 64) * 1024;

    // prologue: stage tile 0 into buffer 0 (V staged like K: rows = dh)
    {
        const unsigned short* kr = kbase + (size_t)srow * 4096 + sseg * 8;
        short8 ka = *(const short8*)kr;
        short8 kb2 = *(const short8*)(kr + (size_t)32 * 4096);
        const unsigned short* vr = vtb + (size_t)srow * 1024 + sseg * 8;
        short8 va = *(const short8*)vr;
        short8 vb2 = *(const short8*)(vr + (size_t)32 * 1024);
        *(short8*)&sK[0][srow * TP + sseg * 8] = ka;
        *(short8*)&sK[0][(32 + srow) * TP + sseg * 8] = kb2;
        *(short8*)&sVt[0][srow * TP + sseg * 8] = va;
        *(short8*)&sVt[0][(32 + srow) * TP + sseg * 8] = vb2;
    }

#pragma unroll 2
    for (int kt = 0; kt < 16; ++kt) {
        const int cur = kt & 1;
        __syncthreads();
        // issue next tile's global loads (completion awaited at ds_write below)
        short8 nka, nkb, nva, nvb;
        if (kt < 15) {
            const int k0n = (kt + 1) * 64;
            const unsigned short* kr = kbase + (size_t)(k0n + srow) * 4096 + sseg * 8;
            nka = *(const short8*)kr;
            nkb = *(const short8*)(kr + (size_t)32 * 4096);
            const unsigned short* vr = vtb + (size_t)srow * 1024 + k0n + sseg * 8;
            nva = *(const short8*)vr;
            nvb = *(const short8*)(vr + (size_t)32 * 1024);
        }
        // --- S^T = K·Q^T with mask-bias accumulator init; exp2; pack bf16 ---
        B4 pfr[2][4];
#pragma unroll
        for (int blk = 0; blk < 2; ++blk) {
            f32x16 c;
            const f32x4* bp = (const f32x4*)&sBias[((kt * 2 + blk) * 2 + hh) * 16];
#pragma unroll
            for (int i = 0; i < 4; ++i) {
                f32x4 x = bp[i];
#pragma unroll
                for (int j = 0; j < 4; ++j) c[i * 4 + j] = x[j];
            }
            __builtin_amdgcn_s_setprio(1);
#pragma unroll
            for (int kc = 0; kc < 4; ++kc) {
                B8 af;
                af.s = *(const short8*)&sK[cur][(blk * 32 + n31) * TP + kc * 16 + hh * 8];
                c = __builtin_amdgcn_mfma_f32_32x32x16_bf16(af.b, qf[kc], c, 0, 0, 0);
            }
            __builtin_amdgcn_s_setprio(0);
#pragma unroll
            for (int gg = 0; gg < 4; ++gg)
#pragma unroll
                for (int j = 0; j < 4; ++j)
                    pfr[blk][gg].b[j] = (__bf16)EXP2(c[gg * 4 + j]);
        }
        // --- O += P·V, l += P·1 ---
#if defined(HAVE_X8)
        __builtin_amdgcn_s_setprio(1);
#pragma unroll
        for (int blk = 0; blk < 2; ++blk) {
#pragma unroll
            for (int gg = 0; gg < 4; ++gg) {
                const int sko = blk * 32 + gg * 8 + hh * 4;
                B4 b0, b1;
                b0.s = *(const short4_*)&sVt[cur][n31 * TP + sko];
                b1.s = *(const short4_*)&sVt[cur][(32 + n31) * TP + sko];
                O0 = __builtin_amdgcn_mfma_f32_32x32x8bf16_1k(pfr[blk][gg].s, b0.s, O0, 0, 0, 0);
                O1 = __builtin_amdgcn_mfma_f32_32x32x8bf16_1k(pfr[blk][gg].s, b1.s, O1, 0, 0, 0);
                L_ = __builtin_amdgcn_mfma_f32_32x32x8bf16_1k(pfr[blk][gg].s, ones.s, L_, 0, 0, 0);
            }
        }
        __builtin_amdgcn_s_setprio(0);
#else
        __builtin_amdgcn_s_setprio(1);
#pragma unroll
        for (int blk = 0; blk < 2; ++blk) {
            B4 par[4];
#pragma unroll
            for (int gg = 0; gg < 4; ++gg) {
                par[gg].i[0] = __shfl_xor(pfr[blk][gg].i[0], 32);
                par[gg].i[1] = __shfl_xor(pfr[blk][gg].i[1], 32);
            }
#pragma unroll
            for (int w = 0; w < 2; ++w) {
                const int gsel = 2 * w + hh;
                B4 lo = (hh == 0) ? pfr[blk][gsel] : par[gsel];
                B4 hi = (hh == 0) ? par[gsel] : pfr[blk][gsel];
                B8 afr;
#pragma unroll
                for (int j = 0; j < 4; ++j) {
                    afr.u[j] = lo.u[j];
                    afr.u[4 + j] = hi.u[j];
                }
                const int sko = blk * 32 + w * 16 + hh * 8;
                B8 b0, b1;
                b0.s = *(const short8*)&sVt[cur][n31 * TP + sko];
                b1.s = *(const short8*)&sVt[cur][(32 + n31) * TP + sko];
                O0 = __builtin_amdgcn_mfma_f32_32x32x16_bf16(afr.b, b0.b, O0, 0, 0, 0);
                O1 = __builtin_amdgcn_mfma_f32_32x32x16_bf16(afr.b, b1.b, O1, 0, 0, 0);
                L_ = __builtin_amdgcn_mfma_f32_32x32x16_bf16(afr.b, ones8.b, L_, 0, 0, 0);
            }
        }
        __builtin_amdgcn_s_setprio(0);
#endif
        // --- write next tile into the other buffer (vmcnt waited here) ---
        if (kt < 15) {
            const int nb = 1 - cur;
            *(short8*)&sK[nb][srow * TP + sseg * 8] = nka;
            *(short8*)&sK[nb][(32 + srow) * TP + sseg * 8] = nkb;
            *(short8*)&sVt[nb][srow * TP + sseg * 8] = nva;
            *(short8*)&sVt[nb][(32 + srow) * TP + sseg * 8] = nvb;
        }
    }

    // --- epilogue: rows q=(r&3)+8*(r>>2)+4*hh; l from ones-MFMA (per-lane) ---
    unsigned short* obase = o + ((size_t)q0w * 4 + b) * 1024 + h * 64 + n31;
#pragma unroll
    for (int r = 0; r < 16; ++r) {
        const int qr = (r & 3) + 8 * (r >> 2) + 4 * hh;
        const float inv = RCP(L_[r]);
        obase[(size_t)qr * 4096] = f2bf_rne(O0[r] * inv);
        obase[(size_t)qr * 4096 + 32] = f2bf_rne(O1[r] * inv);
    }
}

extern "C" void kernel_launch(void* const* d_in, const int* in_sizes, int n_in,
                              void* d_out, int out_size, void* d_ws, size_t ws_size,
                              hipStream_t stream) {
    const float* query = (const float*)d_in[0];
    const float* key_ = (const float*)d_in[1];
    const float* value = (const float*)d_in[2];
    const int* key_mask = (const int*)d_in[3];
    const float* Wq = (const float*)d_in[4];
    const float* bq = (const float*)d_in[5];
    const float* Wk = (const float*)d_in[6];
    const float* bk = (const float*)d_in[7];
    const float* Wv = (const float*)d_in[8];
    const float* bv = (const float*)d_in[9];
    const float* Wo = (const float*)d_in[10];
    const float* bo = (const float*)d_in[11];
    float* out = (float*)d_out;

    const size_t NE = (size_t)4096 * 1024;
    unsigned short* q_ws = (unsigned short*)d_ws;
    unsigned short* k_ws = q_ws + NE;
    unsigned short* v_ws = k_ws + NE;   // holds V^T [(b,h,dh)][s]
    unsigned short* a_ws = v_ws + NE;   // attn output; doubles as qA before attn
    unsigned short* wt_ws = a_ws + NE;  // 4 x 1M bf16 weights

    // activation bf16 scratch: qA in a_ws (dead until attn writes it);
    // kA/vA in d_out (dead until out_gemm writes it; 16MB = 2 x 8MB).
    unsigned short* qA = a_ws;
    unsigned short* kA = (unsigned short*)d_out;
    unsigned short* vA = kA + NE;

    prep<<<dim3(16, 16, 16), 256, 0, stream>>>(Wq, Wk, Wv, Wo, query, key_, value,
                                               wt_ws, qA, kA, vA);
    qkv_gemm<<<dim3(32, 8, 3), 256, 0, stream>>>(qA, kA, vA, wt_ws,
                                                 bq, bk, bv, q_ws, k_ws, v_ws);
    attn_kernel<<<dim3(8, 4, 16), 256, 0, stream>>>(q_ws, k_ws, v_ws, key_mask, a_ws);
    out_gemm<<<dim3(32, 8, 1), 256, 0, stream>>>(a_ws, wt_ws, bo, out);
}

// Round 6
// 194.861 us; speedup vs baseline: 1.2939x; 1.0259x over previous
//
#include <hip/hip_runtime.h>
#include <hip/hip_bf16.h>

// MultiHeadAttention S=1024 B=4 D=1024 H=16 DH=64
// [0] prep: Wq/Wk/Wv/Wo f32 -> bf16 B^T[n][k]  (z=0..3)
//          query/key/value f32 -> bf16 row-major (z=4..15)
// [1] qkv_gemm: 128x128 GEMM, BK=32, 3-buffer 2-deep counted-vmcnt pipeline
//     (R5). p=0,1: Q/K row-major out. p=2: operand-swapped -> V^T directly.
// [2] attn (R6): SAME T3+T4 structure as the GEMM -- K/V staged via
//     global_load_lds (4 DMA/wave/tile), 3 buffers, vmcnt(4) counted waits,
//     raw s_barrier, both-sides XOR granule swizzle (f(row)=row&7) instead of
//     TP=72 padding. No reg staging, no full drains in the k-loop.
// [3] out_gemm (R5 template).
// ws (bf16 elems): q @0, k @NE, vT @2NE, attn_out/qA @3NE, WT(4x1M) @4NE (40MB)

typedef __attribute__((ext_vector_type(8))) short short8;
typedef __attribute__((ext_vector_type(4))) short short4_;
typedef __attribute__((ext_vector_type(4))) float f32x4;
typedef __attribute__((ext_vector_type(16))) float f32x16;
typedef __attribute__((ext_vector_type(8))) __bf16 bf16x8;
typedef __attribute__((ext_vector_type(4))) __bf16 bf16x4;

union B8 {
    short8 s;
    bf16x8 b;
    unsigned short u[8];
};
union B4 {
    short4_ s;
    bf16x4 b;
    unsigned short u[4];
    int i[2];
};

#if __has_builtin(__builtin_amdgcn_exp2f)
#define EXP2(x) __builtin_amdgcn_exp2f(x)
#else
#define EXP2(x) exp2f(x)
#endif
#if __has_builtin(__builtin_amdgcn_rcpf)
#define RCP(x) __builtin_amdgcn_rcpf(x)
#else
#define RCP(x) (1.0f / (x))
#endif

static __device__ __forceinline__ unsigned short f2bf_rne(float f) {
    union { float f; unsigned u; } v; v.f = f;
    unsigned r = v.u + 0x7FFFu + ((v.u >> 16) & 1u);
    return (unsigned short)(r >> 16);
}

static __device__ __forceinline__ void async_lds16(const void* g, const void* l) {
    __builtin_amdgcn_global_load_lds(
        (const __attribute__((address_space(1))) unsigned int*)(unsigned long long)g,
        (__attribute__((address_space(3))) unsigned int*)(unsigned int)(unsigned long long)l,
        16, 0, 0);
}

// ---------------------------------------------------------------------------
// Prep: z<4 weight transpose+convert; z>=4 activation f32->bf16 convert.
// ---------------------------------------------------------------------------
__global__ __launch_bounds__(256) void prep(
    const float* __restrict__ Wq, const float* __restrict__ Wk,
    const float* __restrict__ Wv, const float* __restrict__ Wo,
    const float* __restrict__ query, const float* __restrict__ key,
    const float* __restrict__ value,
    unsigned short* __restrict__ WT,
    unsigned short* __restrict__ qA, unsigned short* __restrict__ kA,
    unsigned short* __restrict__ vA) {
    const int t = threadIdx.x;
    const int z = blockIdx.z;

    if (z >= 4) {
        // activation convert: 12 slices x 1M elems; 256 blocks x 4096 elems.
        const int zz = z - 4;
        const int tensor = zz >> 2;
        const int part = zz & 3;
        const float* src = (tensor == 0) ? query : (tensor == 1) ? key : value;
        unsigned short* dst = (tensor == 0) ? qA : (tensor == 1) ? kA : vA;
        const int blk = blockIdx.y * 16 + blockIdx.x;
        const size_t base = (size_t)part * 1048576 + (size_t)blk * 4096 + t * 16;
        B8 w0, w1;
#pragma unroll
        for (int i = 0; i < 2; ++i) {
            f32x4 a = *(const f32x4*)(src + base + i * 8);
            f32x4 b = *(const f32x4*)(src + base + i * 8 + 4);
#pragma unroll
            for (int j = 0; j < 4; ++j) {
                (i ? w1 : w0).u[j] = f2bf_rne(a[j]);
                (i ? w1 : w0).u[4 + j] = f2bf_rne(b[j]);
            }
        }
        *(short8*)(dst + base) = w0.s;
        *(short8*)(dst + base + 8) = w1.s;
        return;
    }

    __shared__ float sT[64][65];
    const int dtile = blockIdx.x;
    const int sub = blockIdx.y;
    const float* src;
    int spitch;
    unsigned short* dst;
    if (z < 3) {
        const float* W = (z == 0) ? Wq : (z == 1) ? Wk : Wv;
        src = W + (size_t)sub * 65536 + (size_t)dtile * 64 * 64;
        spitch = 64;
        dst = WT + (size_t)z * 1048576 + (size_t)(sub * 64) * 1024 + dtile * 64;
    } else {
        src = Wo + (size_t)dtile * 64 * 1024 + sub * 64;
        spitch = 1024;
        dst = WT + (size_t)3 * 1048576 + (size_t)(sub * 64) * 1024 + dtile * 64;
    }

    const int r = t >> 2;
    const int cseg = (t & 3) * 16;
#pragma unroll
    for (int i = 0; i < 4; ++i) {
        f32x4 v = *(const f32x4*)(src + (size_t)r * spitch + cseg + i * 4);
#pragma unroll
        for (int j = 0; j < 4; ++j) sT[r][cseg + i * 4 + j] = v[j];
    }
    __syncthreads();
    B8 w0, w1;
#pragma unroll
    for (int i = 0; i < 8; ++i) {
        w0.u[i] = f2bf_rne(sT[cseg + i][r]);
        w1.u[i] = f2bf_rne(sT[cseg + 8 + i][r]);
    }
    *(short8*)(dst + (size_t)r * 1024 + cseg) = w0.s;
    *(short8*)(dst + (size_t)r * 1024 + cseg + 8) = w1.s;
}

// ---------------------------------------------------------------------------
// 128x128-tile GEMM, BK=32, 3-buffer 2-deep counted-vmcnt pipeline (R5).
// ---------------------------------------------------------------------------
template <bool OUT_F32, bool BIAS_ROW>
__device__ __forceinline__ void gemm128(unsigned short* __restrict__ sA,
                                        unsigned short* __restrict__ sB,
                                        const unsigned short* __restrict__ A,
                                        size_t lda,
                                        const unsigned short* __restrict__ Bt,
                                        size_t ldb,
                                        const float* __restrict__ bias,
                                        void* __restrict__ Cv, size_t ldc,
                                        float oscale, int row0, int col0) {
    const int t = threadIdx.x;
    const int w = t >> 6;
    const int lane = t & 63;
    const int quad = lane >> 4;
    const int l15 = lane & 15;
    const int wr = w >> 1;
    const int wc = w & 1;
    const int srow16 = lane >> 2;                      // staging row within 16-row chunk
    const int sgseg = (lane & 3) ^ ((lane >> 3) & 3);  // pre-swizzled global 16B seg
    const int rseg = (quad ^ ((l15 >> 1) & 3)) * 8;    // read-side swizzled col (elems)

    f32x4 acc[4][4] = {};

    const unsigned short* agp = A + (size_t)(row0 + w * 32 + srow16) * lda + sgseg * 8;
    const unsigned short* agp2 = agp + (size_t)16 * lda;
    const unsigned short* bgp = Bt + (size_t)(col0 + w * 32 + srow16) * ldb + sgseg * 8;
    const unsigned short* bgp2 = bgp + (size_t)16 * ldb;
    const int ldsA0 = (w * 32) * 32;
    const int ldsA1 = (w * 32 + 16) * 32;

    auto STAGE = [&](int tt, int off) {
        const int k0 = tt * 32;
        async_lds16(agp + k0, sA + off + ldsA0);
        async_lds16(agp2 + k0, sA + off + ldsA1);
        async_lds16(bgp + k0, sB + off + ldsA0);
        async_lds16(bgp2 + k0, sB + off + ldsA1);
    };
    auto COMPUTE = [&](int off) {
        const unsigned short* sac = sA + off;
        const unsigned short* sbc = sB + off;
        B8 af[4], bf[4];
#pragma unroll
        for (int i = 0; i < 4; ++i)
            af[i].s = *(const short8*)&sac[(wr * 64 + i * 16 + l15) * 32 + rseg];
#pragma unroll
        for (int j = 0; j < 4; ++j)
            bf[j].s = *(const short8*)&sbc[(wc * 64 + j * 16 + l15) * 32 + rseg];
#pragma unroll
        for (int i = 0; i < 4; ++i)
#pragma unroll
            for (int j = 0; j < 4; ++j)
                acc[i][j] = __builtin_amdgcn_mfma_f32_16x16x32_bf16(af[i].b, bf[j].b,
                                                                    acc[i][j], 0, 0, 0);
    };

    STAGE(0, 0);
    STAGE(1, 4096);

    for (int t3 = 0; t3 < 30; t3 += 3) {
        asm volatile("s_waitcnt vmcnt(4)" ::: "memory");
        __builtin_amdgcn_s_barrier();
        STAGE(t3 + 2, 8192);
        COMPUTE(0);
        asm volatile("s_waitcnt vmcnt(4)" ::: "memory");
        __builtin_amdgcn_s_barrier();
        STAGE(t3 + 3, 0);
        COMPUTE(4096);
        asm volatile("s_waitcnt vmcnt(4)" ::: "memory");
        __builtin_amdgcn_s_barrier();
        STAGE(t3 + 4, 4096);
        COMPUTE(8192);
    }
    asm volatile("s_waitcnt vmcnt(4)" ::: "memory");
    __builtin_amdgcn_s_barrier();
    COMPUTE(0);
    asm volatile("s_waitcnt vmcnt(0)" ::: "memory");
    __builtin_amdgcn_s_barrier();
    COMPUTE(4096);

    float brow[4][4];
    if constexpr (BIAS_ROW) {
#pragma unroll
        for (int i = 0; i < 4; ++i)
#pragma unroll
            for (int r = 0; r < 4; ++r)
                brow[i][r] = bias[row0 + wr * 64 + i * 16 + quad * 4 + r];
    }
#pragma unroll
    for (int j = 0; j < 4; ++j) {
        const int col = col0 + wc * 64 + j * 16 + l15;
        const float bcol = BIAS_ROW ? 0.0f : bias[col];
#pragma unroll
        for (int i = 0; i < 4; ++i) {
#pragma unroll
            for (int r = 0; r < 4; ++r) {
                const int row = row0 + wr * 64 + i * 16 + quad * 4 + r;
                const size_t idx = (size_t)row * ldc + col;
                const float bb = BIAS_ROW ? brow[i][r] : bcol;
                const float val = (acc[i][j][r] + bb) * oscale;
                if constexpr (OUT_F32)
                    ((float*)Cv)[idx] = val;
                else
                    ((unsigned short*)Cv)[idx] = f2bf_rne(val);
            }
        }
    }
}

#define SCALE_L2E 0.18033688011112042f  // (1/8) * log2(e)

__global__ __launch_bounds__(256) void qkv_gemm(
    const unsigned short* __restrict__ qA, const unsigned short* __restrict__ kA,
    const unsigned short* __restrict__ vA,
    const unsigned short* __restrict__ WT,
    const float* __restrict__ bq, const float* __restrict__ bk, const float* __restrict__ bv,
    unsigned short* q_o, unsigned short* k_o, unsigned short* vT_o) {
    __shared__ unsigned short sA[3 * 128 * 32];
    __shared__ unsigned short sB[3 * 128 * 32];
    const int p = blockIdx.z;
    if (p < 2) {
        const unsigned short* A = (p == 0) ? qA : kA;
        const unsigned short* Bt = WT + (size_t)p * 1048576;
        const float* bias = (p == 0) ? bq : bk;
        unsigned short* C = (p == 0) ? q_o : k_o;
        const float osc = (p == 0) ? SCALE_L2E : 1.0f;  // pre-scale q for attn exp2
        gemm128<false, false>(sA, sB, A, 1024, Bt, 1024, bias, C, 1024, osc,
                              blockIdx.x * 128, blockIdx.y * 128);
    } else {
        // V^T: per batch b, C[colV][s] = sum_d Wv^T[colV][d] * vA[(s*4+b)][d]
        const int b = blockIdx.x >> 3;
        const int rt = blockIdx.x & 7;
        gemm128<false, true>(sA, sB, WT + (size_t)2 * 1048576, 1024,
                             vA + (size_t)b * 1024, 4096, bv,
                             vT_o + (size_t)b * 1048576, 1024, 1.0f,
                             rt * 128, blockIdx.y * 128);
    }
}

__global__ __launch_bounds__(256) void out_gemm(const unsigned short* __restrict__ A,
                                                const unsigned short* __restrict__ WT,
                                                const float* __restrict__ bo,
                                                float* __restrict__ C) {
    __shared__ unsigned short sA[3 * 128 * 32];
    __shared__ unsigned short sB[3 * 128 * 32];
    gemm128<true, false>(sA, sB, A, 1024, WT + (size_t)3 * 1048576, 1024, bo, C, 1024,
                         1.0f, blockIdx.x * 128, blockIdx.y * 128);
}

// ---------------------------------------------------------------------------
// Flash-style attention (R6): 3-buffer global_load_lds staging for K and V,
// counted vmcnt(4), raw s_barrier, both-sides XOR granule swizzle.
// LDS[row][g] holds G[row][g ^ (row&7)] (g = 16B granule 0..7, row stride 128B).
//   write: DMA inst covers 8 rows; lane l -> row l>>3, granule l&7; global
//     granule = (l&7)^(l>>3)  [row&7 == l>>3 since chunk base % 8 == 0]
//   QK read: granule (kc*2+hh) ^ (n31&7)  -> 8 lanes per granule (balanced)
//   PV read: granule (blk*4+gg) ^ (n31&7), half-granule hh*8B
// ---------------------------------------------------------------------------
#if __has_builtin(__builtin_amdgcn_mfma_f32_32x32x8bf16_1k)
#define HAVE_X8 1
#endif

__global__ __launch_bounds__(256) void attn_kernel(
    const unsigned short* __restrict__ q,   // pre-scaled by log2(e)/8
    const unsigned short* __restrict__ k,
    const unsigned short* __restrict__ vT,  // [(b*16+h)*64+dh][s]
    const int* __restrict__ key_mask,
    unsigned short* __restrict__ o) {
    __shared__ unsigned short sK[3 * 64 * 64];
    __shared__ unsigned short sVt[3 * 64 * 64];
    __shared__ float sBias[1024];  // [kt][blk][hh][r]
    __shared__ unsigned long long sBits[16];

    const int t = threadIdx.x;
    const int wave = t >> 6;
    const int lane = t & 63;
    const int n31 = lane & 31;
    const int hh = lane >> 5;
    const int n7 = n31 & 7;

    // XCD-pinning swizzle: all 8 q-tiles of a (b,h) group on one XCD.
    const int L = blockIdx.x + 8 * (blockIdx.y + 4 * blockIdx.z);  // 0..511
    const int xcd = L & 7;
    const int kk = L >> 3;                  // 0..63
    const int g = (xcd << 3) | (kk >> 3);   // (b,h) group 0..63
    const int qt = kk & 7;                  // q-tile 0..7
    const int b = g & 3;
    const int h = g >> 2;
    const int q0w = qt * 128 + wave * 32;

    // mask bits: bit set => masked out
#pragma unroll
    for (int i = 0; i < 4; ++i) {
        const int idx = i * 4 + wave;
        const int sk = idx * 64 + lane;
        unsigned long long bal = __ballot(key_mask[sk * 4 + b] != 0);
        if (lane == 0) sBits[idx] = bal;
    }
    __syncthreads();
    // accumulator-init bias table: -16384 => exp2 underflow => exact 0
#pragma unroll
    for (int i = 0; i < 4; ++i) {
        const int idx = t * 4 + i;  // 0..1023 = [kt][blk][hh][r]
        const int r = idx & 15;
        const int hb = (idx >> 4) & 1;
        const int blk = (idx >> 5) & 1;
        const int kt = idx >> 6;
        const int row = (r & 3) + 8 * (r >> 2) + 4 * hb + blk * 32;
        sBias[idx] = ((sBits[kt] >> row) & 1ull) ? -16384.0f : 0.0f;
    }

    // Q fragments (B-operand of 32x32x16): B[n=lane&31][k=hh*8+j]
    bf16x8 qf[4];
    {
        const unsigned short* qrow =
            q + ((size_t)(q0w + n31) * 4 + b) * 1024 + h * 64 + hh * 8;
#pragma unroll
        for (int kc = 0; kc < 4; ++kc) {
            B8 tmp;
            tmp.s = *(const short8*)(qrow + kc * 16);
            qf[kc] = tmp.b;
        }
    }
    // drain all prologue VMEM (mask + Q) and publish sBias, so in-loop vmcnt
    // counts ONLY the staging DMA.
    __syncthreads();

    f32x16 O0 = {}, O1 = {}, L_ = {};
    B4 ones;
#pragma unroll
    for (int j = 0; j < 4; ++j) ones.u[j] = 0x3F80;  // bf16 1.0
#if !defined(HAVE_X8)
    B8 ones8;
#pragma unroll
    for (int j = 0; j < 8; ++j) ones8.u[j] = 0x3F80;
#endif

    const unsigned short* kbase = k + (size_t)b * 1024 + h * 64;
    const unsigned short* vtb = vT + ((size_t)(b * 16 + h) * 64) * 1024;

    // staging geometry: wave w stages rows w*16..w*16+15 of both K and V
    // (2 DMA insts each); lane l -> row l>>3, pre-swizzled global granule.
    const int lr8 = lane >> 3;
    const int gc = (lane & 7) ^ lr8;
    const unsigned short* kst0 = kbase + (size_t)(wave * 16 + lr8) * 4096 + gc * 8;
    const unsigned short* kst1 = kst0 + (size_t)8 * 4096;
    const unsigned short* vst0 = vtb + (size_t)(wave * 16 + lr8) * 1024 + gc * 8;
    const unsigned short* vst1 = vst0 + (size_t)8 * 1024;
    const int lds0 = (wave * 16) * 64;
    const int lds1 = (wave * 16 + 8) * 64;

    auto STAGE = [&](int tt, int boff) {
        const size_t k0 = (size_t)tt * 64;
        async_lds16(kst0 + k0 * 4096, sK + boff + lds0);
        async_lds16(kst1 + k0 * 4096, sK + boff + lds1);
        async_lds16(vst0 + k0, sVt + boff + lds0);
        async_lds16(vst1 + k0, sVt + boff + lds1);
    };

    auto ITER = [&](int kt, int curB, int stT, int stB, bool doStage, bool last) {
        if (last)
            asm volatile("s_waitcnt vmcnt(0)" ::: "memory");
        else
            asm volatile("s_waitcnt vmcnt(4)" ::: "memory");
        __builtin_amdgcn_s_barrier();
        if (doStage) STAGE(stT, stB);
        const unsigned short* sKc = sK + curB;
        const unsigned short* sVc = sVt + curB;
        // --- S^T = K·Q^T with mask-bias accumulator init; exp2; pack bf16 ---
        B4 pfr[2][4];
#pragma unroll
        for (int blk = 0; blk < 2; ++blk) {
            f32x16 c;
            const f32x4* bp = (const f32x4*)&sBias[((kt * 2 + blk) * 2 + hh) * 16];
#pragma unroll
            for (int i = 0; i < 4; ++i) {
                f32x4 x = bp[i];
#pragma unroll
                for (int j = 0; j < 4; ++j) c[i * 4 + j] = x[j];
            }
            __builtin_amdgcn_s_setprio(1);
#pragma unroll
            for (int kc = 0; kc < 4; ++kc) {
                B8 af;
                af.s = *(const short8*)&sKc[(blk * 32 + n31) * 64 +
                                            (((kc * 2 + hh) ^ n7) << 3)];
                c = __builtin_amdgcn_mfma_f32_32x32x16_bf16(af.b, qf[kc], c, 0, 0, 0);
            }
            __builtin_amdgcn_s_setprio(0);
#pragma unroll
            for (int gg = 0; gg < 4; ++gg)
#pragma unroll
                for (int j = 0; j < 4; ++j)
                    pfr[blk][gg].b[j] = (__bf16)EXP2(c[gg * 4 + j]);
        }
        // --- O += P·V, l += P·1 ---
#if defined(HAVE_X8)
        __builtin_amdgcn_s_setprio(1);
#pragma unroll
        for (int blk = 0; blk < 2; ++blk) {
#pragma unroll
            for (int gg = 0; gg < 4; ++gg) {
                const int sg = (((blk * 4 + gg) ^ n7) << 3) + hh * 4;
                B4 b0, b1;
                b0.s = *(const short4_*)&sVc[n31 * 64 + sg];
                b1.s = *(const short4_*)&sVc[(32 + n31) * 64 + sg];
                O0 = __builtin_amdgcn_mfma_f32_32x32x8bf16_1k(pfr[blk][gg].s, b0.s, O0, 0, 0, 0);
                O1 = __builtin_amdgcn_mfma_f32_32x32x8bf16_1k(pfr[blk][gg].s, b1.s, O1, 0, 0, 0);
                L_ = __builtin_amdgcn_mfma_f32_32x32x8bf16_1k(pfr[blk][gg].s, ones.s, L_, 0, 0, 0);
            }
        }
        __builtin_amdgcn_s_setprio(0);
#else
        __builtin_amdgcn_s_setprio(1);
#pragma unroll
        for (int blk = 0; blk < 2; ++blk) {
            B4 par[4];
#pragma unroll
            for (int gg = 0; gg < 4; ++gg) {
                par[gg].i[0] = __shfl_xor(pfr[blk][gg].i[0], 32);
                par[gg].i[1] = __shfl_xor(pfr[blk][gg].i[1], 32);
            }
#pragma unroll
            for (int w2 = 0; w2 < 2; ++w2) {
                const int gsel = 2 * w2 + hh;
                B4 lo = (hh == 0) ? pfr[blk][gsel] : par[gsel];
                B4 hi = (hh == 0) ? par[gsel] : pfr[blk][gsel];
                B8 afr;
#pragma unroll
                for (int j = 0; j < 4; ++j) {
                    afr.u[j] = lo.u[j];
                    afr.u[4 + j] = hi.u[j];
                }
                const int cg = blk * 4 + w2 * 2 + hh;
                const int sg = (cg ^ n7) << 3;
                B8 b0, b1;
                b0.s = *(const short8*)&sVc[n31 * 64 + sg];
                b1.s = *(const short8*)&sVc[(32 + n31) * 64 + sg];
                O0 = __builtin_amdgcn_mfma_f32_32x32x16_bf16(afr.b, b0.b, O0, 0, 0, 0);
                O1 = __builtin_amdgcn_mfma_f32_32x32x16_bf16(afr.b, b1.b, O1, 0, 0, 0);
                L_ = __builtin_amdgcn_mfma_f32_32x32x16_bf16(afr.b, ones8.b, L_, 0, 0, 0);
            }
        }
        __builtin_amdgcn_s_setprio(0);
#endif
    };

    // prologue: tiles 0,1 in flight (8 DMA insts/wave outstanding)
    STAGE(0, 0);
    STAGE(1, 4096);
    // tiles 0..11 (4 runtime iterations x 3), stages up to tile 13
    for (int t3 = 0; t3 < 12; t3 += 3) {
        ITER(t3, 0, t3 + 2, 8192, true, false);
        ITER(t3 + 1, 4096, t3 + 3, 0, true, false);
        ITER(t3 + 2, 8192, t3 + 4, 4096, true, false);
    }
    ITER(12, 0, 14, 8192, true, false);
    ITER(13, 4096, 15, 0, true, false);
    ITER(14, 8192, 0, 0, false, false);  // vmcnt(4): stage(15) may stay in flight
    ITER(15, 0, 0, 0, false, true);      // vmcnt(0)

    // --- epilogue: rows q=(r&3)+8*(r>>2)+4*hh; l from ones-MFMA (per-lane) ---
    unsigned short* obase = o + ((size_t)q0w * 4 + b) * 1024 + h * 64 + n31;
#pragma unroll
    for (int r = 0; r < 16; ++r) {
        const int qr = (r & 3) + 8 * (r >> 2) + 4 * hh;
        const float inv = RCP(L_[r]);
        obase[(size_t)qr * 4096] = f2bf_rne(O0[r] * inv);
        obase[(size_t)qr * 4096 + 32] = f2bf_rne(O1[r] * inv);
    }
}

extern "C" void kernel_launch(void* const* d_in, const int* in_sizes, int n_in,
                              void* d_out, int out_size, void* d_ws, size_t ws_size,
                              hipStream_t stream) {
    const float* query = (const float*)d_in[0];
    const float* key_ = (const float*)d_in[1];
    const float* value = (const float*)d_in[2];
    const int* key_mask = (const int*)d_in[3];
    const float* Wq = (const float*)d_in[4];
    const float* bq = (const float*)d_in[5];
    const float* Wk = (const float*)d_in[6];
    const float* bk = (const float*)d_in[7];
    const float* Wv = (const float*)d_in[8];
    const float* bv = (const float*)d_in[9];
    const float* Wo = (const float*)d_in[10];
    const float* bo = (const float*)d_in[11];
    float* out = (float*)d_out;

    const size_t NE = (size_t)4096 * 1024;
    unsigned short* q_ws = (unsigned short*)d_ws;
    unsigned short* k_ws = q_ws + NE;
    unsigned short* v_ws = k_ws + NE;   // holds V^T [(b,h,dh)][s]
    unsigned short* a_ws = v_ws + NE;   // attn output; doubles as qA before attn
    unsigned short* wt_ws = a_ws + NE;  // 4 x 1M bf16 weights

    // activation bf16 scratch: qA in a_ws (dead until attn writes it);
    // kA/vA in d_out (dead until out_gemm writes it; 16MB = 2 x 8MB).
    unsigned short* qA = a_ws;
    unsigned short* kA = (unsigned short*)d_out;
    unsigned short* vA = kA + NE;

    prep<<<dim3(16, 16, 16), 256, 0, stream>>>(Wq, Wk, Wv, Wo, query, key_, value,
                                               wt_ws, qA, kA, vA);
    qkv_gemm<<<dim3(32, 8, 3), 256, 0, stream>>>(qA, kA, vA, wt_ws,
                                                 bq, bk, bv, q_ws, k_ws, v_ws);
    attn_kernel<<<dim3(8, 4, 16), 256, 0, stream>>>(q_ws, k_ws, v_ws, key_mask, a_ws);
    out_gemm<<<dim3(32, 8, 1), 256, 0, stream>>>(a_ws, wt_ws, bo, out);
}